// Round 1
// baseline (1937.331 us; speedup 1.0000x reference)
//
#include <hip/hip_runtime.h>

#define EPSV 1e-5f

// ---------------------------------------------------------------- lin1 + stats
// wave per node: lane l computes cols l and l+64 of t = x @ lin1_w + lin1_b
__global__ void k_lin1(const float* __restrict__ x, const float* __restrict__ w,
                       const float* __restrict__ bvec, float* __restrict__ outb,
                       float* __restrict__ stats, int N)
{
    int l  = threadIdx.x & 63;
    int wv = threadIdx.x >> 6;
    int waveSlots = gridDim.x * 4;
    int trips = (N + waveSlots - 1) / waveSlots;
    float s0 = 0.f, q0 = 0.f, s1 = 0.f, q1 = 0.f;
    for (int it = 0; it < trips; ++it) {
        int n = (it * gridDim.x + blockIdx.x) * 4 + wv;
        if (n < N) {
            const float* xr = x + (size_t)n * 27;
            float a0 = bvec[l], a1 = bvec[64 + l];
            #pragma unroll
            for (int k = 0; k < 27; ++k) {
                float xv = xr[k];
                a0 = fmaf(xv, w[k * 128 + l], a0);
                a1 = fmaf(xv, w[k * 128 + 64 + l], a1);
            }
            outb[(size_t)n * 128 + l] = a0;
            outb[(size_t)n * 128 + 64 + l] = a1;
            s0 += a0; q0 += a0 * a0; s1 += a1; q1 += a1 * a1;
        }
    }
    __shared__ float sred[4][256];
    sred[0][threadIdx.x] = s0; sred[1][threadIdx.x] = q0;
    sred[2][threadIdx.x] = s1; sred[3][threadIdx.x] = q1;
    __syncthreads();
    if (threadIdx.x < 64) {
        int t = threadIdx.x;
        float v0 = sred[0][t] + sred[0][t + 64] + sred[0][t + 128] + sred[0][t + 192];
        float v1 = sred[1][t] + sred[1][t + 64] + sred[1][t + 128] + sred[1][t + 192];
        float v2 = sred[2][t] + sred[2][t + 64] + sred[2][t + 128] + sred[2][t + 192];
        float v3 = sred[3][t] + sred[3][t + 64] + sred[3][t + 128] + sred[3][t + 192];
        atomicAdd(stats + t, v0);          // sum col l
        atomicAdd(stats + 128 + t, v1);    // sq  col l
        atomicAdd(stats + 64 + t, v2);     // sum col l+64
        atomicAdd(stats + 192 + t, v3);    // sq  col l+64
    }
}

// ---------------------------------------------------------------- BN apply
// h = relu(bn(t)) or h += relu(bn(t)); stats = [sum(128), sumsq(128)]
__global__ void k_bnapply(const float* __restrict__ t, float* __restrict__ h,
                          const float* __restrict__ stats,
                          const float* __restrict__ gamma, const float* __restrict__ beta,
                          float invR, int n4, int residual)
{
    __shared__ float sc[128], sh[128];
    if (threadIdx.x < 128) {
        float mu  = stats[threadIdx.x] * invR;
        float var = stats[128 + threadIdx.x] * invR - mu * mu;
        float s   = gamma[threadIdx.x] * rsqrtf(var + EPSV);
        sc[threadIdx.x] = s;
        sh[threadIdx.x] = beta[threadIdx.x] - mu * s;
    }
    __syncthreads();
    const float4* t4 = (const float4*)t;
    float4* h4 = (float4*)h;
    int stride = gridDim.x * blockDim.x;
    for (int i = blockIdx.x * blockDim.x + threadIdx.x; i < n4; i += stride) {
        int c = (i * 4) & 127;
        float4 v = t4[i];
        float4 r;
        r.x = fmaxf(v.x * sc[c]     + sh[c],     0.f);
        r.y = fmaxf(v.y * sc[c + 1] + sh[c + 1], 0.f);
        r.z = fmaxf(v.z * sc[c + 2] + sh[c + 2], 0.f);
        r.w = fmaxf(v.w * sc[c + 3] + sh[c + 3], 0.f);
        if (residual) {
            float4 hv = h4[i];
            r.x += hv.x; r.y += hv.y; r.z += hv.z; r.w += hv.w;
        }
        h4[i] = r;
    }
}

// ---------------------------------------------------------------- CSR build
__global__ void k_deg(const int* __restrict__ dst, int* __restrict__ cnt, int E)
{
    int stride = gridDim.x * blockDim.x;
    for (int e = blockIdx.x * blockDim.x + threadIdx.x; e < E; e += stride)
        atomicAdd(cnt + dst[e], 1);
}

__global__ void k_scan1(const int* __restrict__ cnt, int* __restrict__ rowptr,
                        int* __restrict__ bsum, int N)
{
    __shared__ int sb[256];
    int i = blockIdx.x * 256 + threadIdx.x;
    int v = (i < N) ? cnt[i] : 0;
    sb[threadIdx.x] = v;
    __syncthreads();
    for (int ofs = 1; ofs < 256; ofs <<= 1) {
        int u = (threadIdx.x >= ofs) ? sb[threadIdx.x - ofs] : 0;
        __syncthreads();
        sb[threadIdx.x] += u;
        __syncthreads();
    }
    if (i < N) rowptr[i] = sb[threadIdx.x] - v;  // exclusive within block
    if (threadIdx.x == 255) bsum[blockIdx.x] = sb[255];
}

__global__ void k_scan2(int* __restrict__ bs, int nb)
{
    __shared__ int sb[512];
    int t = threadIdx.x;
    int v = (t < nb) ? bs[t] : 0;
    sb[t] = v;
    __syncthreads();
    for (int ofs = 1; ofs < 512; ofs <<= 1) {
        int u = (t >= ofs) ? sb[t - ofs] : 0;
        __syncthreads();
        sb[t] += u;
        __syncthreads();
    }
    bs[t] = sb[t] - v;  // exclusive
}

__global__ void k_scan3(int* __restrict__ rowptr, const int* __restrict__ bsum,
                        int N, int E)
{
    int i = blockIdx.x * blockDim.x + threadIdx.x;
    if (i < N) rowptr[i] += bsum[i >> 8];
    if (i == 0) rowptr[N] = E;
}

__global__ void k_scatter(const int* __restrict__ src, const int* __restrict__ dst,
                          const int* __restrict__ rowptr, int* __restrict__ cursor,
                          int* __restrict__ csr, int E)
{
    int stride = gridDim.x * blockDim.x;
    for (int e = blockIdx.x * blockDim.x + threadIdx.x; e < E; e += stride) {
        int d = dst[e];
        int pos = atomicAdd(cursor + d, 1);
        csr[rowptr[d] + pos] = src[e];
    }
}

// ---------------------------------------------------------------- fused GEMM
// bc[n, 0:64)   = h[n,:] @ bases_w[l]
// bc[n, 64:160) = h[n,:] @ comb_w[l] + comb_b[l]
// block 512 (8 waves), 64 nodes per block-iter, W transposed in LDS (pad->129)
__global__ __launch_bounds__(512)
void k_gemm160(const float* __restrict__ h, const float* __restrict__ basesW,
               const float* __restrict__ combW, const float* __restrict__ combB,
               float* __restrict__ bc, int N)
{
    __shared__ float Wt[160 * 129];     // [c][k] stride 129: bank (c+k)%32 -> 2 lanes/bank
    __shared__ float hbuf[64 * 128];
    int tid = threadIdx.x;
    for (int i = tid; i < 128 * 64; i += 512) {        // bases: i = k*64+c (coalesced)
        int k = i >> 6, c = i & 63;
        Wt[c * 129 + k] = basesW[i];
    }
    for (int i = tid; i < 128 * 96; i += 512) {        // comb: i = k*96+c (coalesced)
        int k = i / 96, c = i - k * 96;
        Wt[(64 + c) * 129 + k] = combW[i];
    }
    __syncthreads();

    int l = tid & 63, w = tid >> 6;
    int trips = (N + 64 * gridDim.x - 1) / (64 * gridDim.x);
    float b1 = combB[l];
    float b2 = (l < 32) ? combB[64 + l] : 0.f;
    for (int it = 0; it < trips; ++it) {
        int base = (it * gridDim.x + blockIdx.x) * 64;
        __syncthreads();   // hbuf WAR guard
        for (int i = tid; i < 64 * 128; i += 512) {
            int node = base + (i >> 7);
            hbuf[i] = (node < N) ? h[(size_t)node * 128 + (i & 127)] : 0.f;
        }
        __syncthreads();
        int m0 = w * 8;
        float acc0[8], acc1[8], acc2[8];
        #pragma unroll
        for (int m = 0; m < 8; ++m) { acc0[m] = 0.f; acc1[m] = 0.f; acc2[m] = 0.f; }
        for (int k = 0; k < 128; k += 4) {
            float4 hv[8];
            #pragma unroll
            for (int m = 0; m < 8; ++m)
                hv[m] = *(const float4*)&hbuf[(m0 + m) * 128 + k];
            #pragma unroll
            for (int kk = 0; kk < 4; ++kk) {
                float w0 = Wt[l * 129 + k + kk];
                float w1 = Wt[(l + 64) * 129 + k + kk];
                float w2 = (l < 32) ? Wt[(l + 128) * 129 + k + kk] : 0.f;
                #pragma unroll
                for (int m = 0; m < 8; ++m) {
                    float hx = ((const float*)&hv[m])[kk];
                    acc0[m] = fmaf(hx, w0, acc0[m]);
                    acc1[m] = fmaf(hx, w1, acc1[m]);
                    acc2[m] = fmaf(hx, w2, acc2[m]);
                }
            }
        }
        #pragma unroll
        for (int m = 0; m < 8; ++m) {
            int node = base + m0 + m;
            if (node < N) {
                bc[(size_t)node * 160 + l]       = acc0[m];
                bc[(size_t)node * 160 + 64 + l]  = acc1[m] + b1;
                if (l < 32)
                    bc[(size_t)node * 160 + 128 + l] = acc2[m] + b2;
            }
        }
    }
}

// ---------------------------------------------------------------- aggregation
// wave per node: sum/mean/max over incoming edges (self-loop implicit), then
// einsum with comb, + conv_bias, write out, accumulate BN stats.
__global__ void k_agg(const float* __restrict__ bc, const int* __restrict__ csr,
                      const int* __restrict__ rowptr, const float* __restrict__ cbias,
                      float* __restrict__ outb, float* __restrict__ stats, int N)
{
    __shared__ float aggL[4][3][64];
    __shared__ float combL[4][96];
    __shared__ float sred[4][256];
    int l = threadIdx.x & 63;
    int w = threadIdx.x >> 6;
    int waveSlots = gridDim.x * 4;
    int trips = (N + waveSlots - 1) / waveSlots;
    float s0 = 0.f, q0 = 0.f, s1 = 0.f, q1 = 0.f;
    for (int it = 0; it < trips; ++it) {
        int n = (it * gridDim.x + blockIdx.x) * 4 + w;
        bool act = n < N;
        if (act) {
            int row0 = rowptr[n], row1 = rowptr[n + 1];
            int cnt = row1 - row0;
            const float* myb = bc + (size_t)n * 160;
            float sv = myb[l];
            float sm = sv, mx = sv;             // self loop
            int j = 0;
            while (j < cnt) {
                int chunk = min(64, cnt - j);
                int idx = (l < chunk) ? csr[row0 + j + l] : 0;
                for (int tt = 0; tt < chunk; ++tt) {
                    int sn = __shfl(idx, tt, 64);
                    float v = bc[(size_t)sn * 160 + l];
                    sm += v;
                    mx = fmaxf(mx, v);
                }
                j += chunk;
            }
            float dg = (float)(cnt + 1);
            aggL[w][0][l] = sm;
            aggL[w][1][l] = sm / dg;
            aggL[w][2][l] = mx;
            combL[w][l] = myb[64 + l];
            if (l < 32) combL[w][64 + l] = myb[128 + l];
        }
        __syncthreads();
        if (act) {
            int h0 = l >> 4, f = l & 15;
            float o0 = cbias[l], o1 = cbias[64 + l];
            #pragma unroll
            for (int a = 0; a < 3; ++a) {
                #pragma unroll
                for (int b2 = 0; b2 < 4; ++b2) {
                    float ag = aggL[w][a][b2 * 16 + f];
                    o0 = fmaf(combL[w][h0 * 12 + a * 4 + b2], ag, o0);
                    o1 = fmaf(combL[w][(h0 + 4) * 12 + a * 4 + b2], ag, o1);
                }
            }
            outb[(size_t)n * 128 + l] = o0;
            outb[(size_t)n * 128 + 64 + l] = o1;
            s0 += o0; q0 += o0 * o0; s1 += o1; q1 += o1 * o1;
        }
        __syncthreads();
    }
    sred[0][threadIdx.x] = s0; sred[1][threadIdx.x] = q0;
    sred[2][threadIdx.x] = s1; sred[3][threadIdx.x] = q1;
    __syncthreads();
    if (threadIdx.x < 64) {
        int t = threadIdx.x;
        float v0 = sred[0][t] + sred[0][t + 64] + sred[0][t + 128] + sred[0][t + 192];
        float v1 = sred[1][t] + sred[1][t + 64] + sred[1][t + 128] + sred[1][t + 192];
        float v2 = sred[2][t] + sred[2][t + 64] + sred[2][t + 128] + sred[2][t + 192];
        float v3 = sred[3][t] + sred[3][t + 64] + sred[3][t + 128] + sred[3][t + 192];
        atomicAdd(stats + t, v0);
        atomicAdd(stats + 128 + t, v1);
        atomicAdd(stats + 64 + t, v2);
        atomicAdd(stats + 192 + t, v3);
    }
}

// ---------------------------------------------------------------- pooling
__global__ void k_gbound(const int* __restrict__ batch, int* __restrict__ gstart,
                         int N, int G)
{
    int stride = gridDim.x * blockDim.x;
    for (int n = blockIdx.x * blockDim.x + threadIdx.x; n < N; n += stride) {
        int b = batch[n];
        if (n == 0) {
            for (int g = 0; g <= b; ++g) gstart[g] = 0;
        } else {
            int pb = batch[n - 1];
            for (int g = pb + 1; g <= b; ++g) gstart[g] = n;
        }
        if (n == N - 1) {
            for (int g = b + 1; g <= G; ++g) gstart[g] = N;
        }
    }
}

__global__ void k_gmean(const float* __restrict__ h, const int* __restrict__ gstart,
                        float* __restrict__ gout, int G)
{
    int g = blockIdx.x;
    if (g >= G) return;
    int s = gstart[g], e = gstart[g + 1];
    float acc = 0.f;
    for (int n = s; n < e; ++n) acc += h[(size_t)n * 128 + threadIdx.x];
    float cntf = fmaxf((float)(e - s), 1.f);
    gout[g * 128 + threadIdx.x] = acc / cntf;
}

// ---------------------------------------------------------------- MLP
__global__ void k_mlp1(const float* __restrict__ gin, const float* __restrict__ w1,
                       float* __restrict__ t1, float* __restrict__ stats, int G)
{
    int g = blockIdx.x;
    int c = threadIdx.x;  // block 64
    const float* gr = gin + g * 128;
    float acc = 0.f;
    for (int k = 0; k < 128; ++k) acc = fmaf(gr[k], w1[k * 64 + c], acc);
    t1[g * 64 + c] = acc;
    atomicAdd(stats + c, acc);
    atomicAdd(stats + 64 + c, acc * acc);
}

__global__ void k_mlp2(const float* __restrict__ t1, const float* __restrict__ stats1,
                       const float* __restrict__ g1, const float* __restrict__ b1,
                       const float* __restrict__ w2, float* __restrict__ t2,
                       float* __restrict__ stats2, float invG, int G)
{
    __shared__ float row[64];
    int g = blockIdx.x;
    int c = threadIdx.x;  // block 64
    float v = t1[g * 64 + c];
    float mu = stats1[c] * invG;
    float var = stats1[64 + c] * invG - mu * mu;
    row[c] = fmaxf(g1[c] * (v - mu) * rsqrtf(var + EPSV) + b1[c], 0.f);
    __syncthreads();
    if (c < 32) {
        float acc = 0.f;
        #pragma unroll
        for (int k = 0; k < 64; ++k) acc = fmaf(row[k], w2[k * 32 + c], acc);
        t2[g * 32 + c] = acc;
        atomicAdd(stats2 + c, acc);
        atomicAdd(stats2 + 32 + c, acc * acc);
    }
}

__global__ void k_mlp3(const float* __restrict__ t2, const float* __restrict__ stats2,
                       const float* __restrict__ g2, const float* __restrict__ b2,
                       const float* __restrict__ w3, const float* __restrict__ b3,
                       float* __restrict__ out, float invG, int G)
{
    __shared__ float row[32];
    int g = blockIdx.x;
    int c = threadIdx.x;  // block 64
    if (c < 32) {
        float v = t2[g * 32 + c];
        float mu = stats2[c] * invG;
        float var = stats2[32 + c] * invG - mu * mu;
        row[c] = fmaxf(g2[c] * (v - mu) * rsqrtf(var + EPSV) + b2[c], 0.f);
    }
    __syncthreads();
    if (c < 10) {
        float acc = b3[c];
        #pragma unroll
        for (int k = 0; k < 32; ++k) acc = fmaf(row[k], w3[k * 10 + c], acc);
        out[g * 10 + c] = acc;
    }
}

// ---------------------------------------------------------------- launch
extern "C" void kernel_launch(void* const* d_in, const int* in_sizes, int n_in,
                              void* d_out, int out_size, void* d_ws, size_t ws_size,
                              hipStream_t stream)
{
    const float* x        = (const float*)d_in[0];
    const float* lin1_w   = (const float*)d_in[1];
    const float* lin1_b   = (const float*)d_in[2];
    const float* bn1_g    = (const float*)d_in[3];
    const float* bn1_b    = (const float*)d_in[4];
    const float* bases_w  = (const float*)d_in[5];
    const float* comb_w   = (const float*)d_in[6];
    const float* comb_b   = (const float*)d_in[7];
    const float* conv_bias= (const float*)d_in[8];
    const float* bn_g     = (const float*)d_in[9];
    const float* bn_b     = (const float*)d_in[10];
    const float* mlp_w1   = (const float*)d_in[11];
    const float* mbn1_g   = (const float*)d_in[12];
    const float* mbn1_b   = (const float*)d_in[13];
    const float* mlp_w2   = (const float*)d_in[14];
    const float* mbn2_g   = (const float*)d_in[15];
    const float* mbn2_b   = (const float*)d_in[16];
    const float* mlp_w3   = (const float*)d_in[17];
    const float* mlp_b3   = (const float*)d_in[18];
    const int*   edge_idx = (const int*)d_in[19];
    const int*   batch    = (const int*)d_in[20];
    float* outp = (float*)d_out;

    const int N = in_sizes[20];
    const int E = in_sizes[19] / 2;
    const int G = out_size / 10;
    const int* esrc = edge_idx;
    const int* edst = edge_idx + E;

    // ----- workspace carve -----
    char* p = (char*)d_ws;
    auto alloc = [&](size_t bytes) {
        char* r = p;
        p += (bytes + 255) & ~(size_t)255;
        return r;
    };
    float* h      = (float*)alloc((size_t)N * 128 * 4);
    float* bc     = (float*)alloc((size_t)N * 160 * 4);
    float* outb   = (float*)alloc((size_t)N * 128 * 4);
    int*   csr    = (int*)  alloc((size_t)E * 4);
    int*   rowptr = (int*)  alloc((size_t)(N + 1) * 4);
    float* tg     = (float*)alloc((size_t)G * 128 * 4);
    float* t1     = (float*)alloc((size_t)G * 64 * 4);
    float* t2     = (float*)alloc((size_t)G * 32 * 4);
    int*   gstart = (int*)  alloc((size_t)(G + 1) * 4);
    int*   bsum   = (int*)  alloc(512 * 4);
    char*  zbase  = p;
    int*   cnt    = (int*)  alloc((size_t)N * 4);
    int*   cursor = (int*)  alloc((size_t)N * 4);
    float* stats  = (float*)alloc(7 * 256 * 4);
    size_t zbytes = (size_t)(p - zbase);
    (void)ws_size; (void)n_in;

    hipMemsetAsync(zbase, 0, zbytes, stream);

    const float invN = 1.0f / (float)N;
    const float invG = 1.0f / (float)G;
    const int nb = (N + 255) / 256;
    const int n4 = N * 32;  // N*128/4

    // lin1 + BN1 stats
    k_lin1<<<1024, 256, 0, stream>>>(x, lin1_w, lin1_b, outb, stats, N);
    // CSR build
    k_deg<<<1024, 256, 0, stream>>>(edst, cnt, E);
    k_scan1<<<nb, 256, 0, stream>>>(cnt, rowptr, bsum, N);
    k_scan2<<<1, 512, 0, stream>>>(bsum, nb);
    k_scan3<<<nb, 256, 0, stream>>>(rowptr, bsum, N, E);
    k_scatter<<<1024, 256, 0, stream>>>(esrc, edst, rowptr, cursor, csr, E);
    // BN1 apply -> h
    k_bnapply<<<2048, 256, 0, stream>>>(outb, h, stats, bn1_g, bn1_b, invN, n4, 0);

    for (int l = 0; l < 4; ++l) {
        const float* bw = bases_w + (size_t)l * 128 * 64;
        const float* cw = comb_w + (size_t)l * 128 * 96;
        const float* cb = comb_b + (size_t)l * 96;
        const float* cvb = conv_bias + (size_t)l * 128;
        float* st = stats + (1 + l) * 256;
        k_gemm160<<<256, 512, 0, stream>>>(h, bw, cw, cb, bc, N);
        k_agg<<<1024, 256, 0, stream>>>(bc, csr, rowptr, cvb, outb, st, N);
        k_bnapply<<<2048, 256, 0, stream>>>(outb, h, st, bn_g + l * 128, bn_b + l * 128,
                                            invN, n4, 1);
    }

    // pooling
    k_gbound<<<512, 256, 0, stream>>>(batch, gstart, N, G);
    k_gmean<<<G, 128, 0, stream>>>(h, gstart, tg, G);
    // MLP
    float* st5 = stats + 5 * 256;
    float* st6 = stats + 6 * 256;
    k_mlp1<<<G, 64, 0, stream>>>(tg, mlp_w1, t1, st5, G);
    k_mlp2<<<G, 64, 0, stream>>>(t1, st5, mbn1_g, mbn1_b, mlp_w2, t2, st6, invG, G);
    k_mlp3<<<G, 64, 0, stream>>>(t2, st6, mbn2_g, mbn2_b, mlp_w3, mlp_b3, outp, invG, G);
}

// Round 2
// 1860.365 us; speedup vs baseline: 1.0414x; 1.0414x over previous
//
#include <hip/hip_runtime.h>

#define EPSV 1e-5f

__device__ __forceinline__ float bf2f(unsigned short u) {
    union { unsigned i; float f; } c; c.i = ((unsigned)u) << 16; return c.f;
}
__device__ __forceinline__ unsigned short f2bf(float f) {
    union { float f; unsigned i; } c; c.f = f;
    unsigned r = c.i + 0x7fff + ((c.i >> 16) & 1);
    return (unsigned short)(r >> 16);
}

// ---------------------------------------------------------------- lin1 + stats
__global__ void k_lin1(const float* __restrict__ x, const float* __restrict__ w,
                       const float* __restrict__ bvec, float* __restrict__ outb,
                       float* __restrict__ stats, int N)
{
    int l  = threadIdx.x & 63;
    int wv = threadIdx.x >> 6;
    int waveSlots = gridDim.x * 4;
    int trips = (N + waveSlots - 1) / waveSlots;
    float s0 = 0.f, q0 = 0.f, s1 = 0.f, q1 = 0.f;
    for (int it = 0; it < trips; ++it) {
        int n = (it * gridDim.x + blockIdx.x) * 4 + wv;
        if (n < N) {
            const float* xr = x + (size_t)n * 27;
            float a0 = bvec[l], a1 = bvec[64 + l];
            #pragma unroll
            for (int k = 0; k < 27; ++k) {
                float xv = xr[k];
                a0 = fmaf(xv, w[k * 128 + l], a0);
                a1 = fmaf(xv, w[k * 128 + 64 + l], a1);
            }
            outb[(size_t)n * 128 + l] = a0;
            outb[(size_t)n * 128 + 64 + l] = a1;
            s0 += a0; q0 += a0 * a0; s1 += a1; q1 += a1 * a1;
        }
    }
    __shared__ float sred[4][256];
    sred[0][threadIdx.x] = s0; sred[1][threadIdx.x] = q0;
    sred[2][threadIdx.x] = s1; sred[3][threadIdx.x] = q1;
    __syncthreads();
    if (threadIdx.x < 64) {
        int t = threadIdx.x;
        float v0 = sred[0][t] + sred[0][t + 64] + sred[0][t + 128] + sred[0][t + 192];
        float v1 = sred[1][t] + sred[1][t + 64] + sred[1][t + 128] + sred[1][t + 192];
        float v2 = sred[2][t] + sred[2][t + 64] + sred[2][t + 128] + sred[2][t + 192];
        float v3 = sred[3][t] + sred[3][t + 64] + sred[3][t + 128] + sred[3][t + 192];
        atomicAdd(stats + t, v0);
        atomicAdd(stats + 128 + t, v1);
        atomicAdd(stats + 64 + t, v2);
        atomicAdd(stats + 192 + t, v3);
    }
}

// ---------------------------------------------------------------- BN apply
__global__ void k_bnapply(const float* __restrict__ t, float* __restrict__ h,
                          const float* __restrict__ stats,
                          const float* __restrict__ gamma, const float* __restrict__ beta,
                          float invR, int n4, int residual)
{
    __shared__ float sc[128], sh[128];
    if (threadIdx.x < 128) {
        float mu  = stats[threadIdx.x] * invR;
        float var = stats[128 + threadIdx.x] * invR - mu * mu;
        float s   = gamma[threadIdx.x] * rsqrtf(var + EPSV);
        sc[threadIdx.x] = s;
        sh[threadIdx.x] = beta[threadIdx.x] - mu * s;
    }
    __syncthreads();
    const float4* t4 = (const float4*)t;
    float4* h4 = (float4*)h;
    int stride = gridDim.x * blockDim.x;
    for (int i = blockIdx.x * blockDim.x + threadIdx.x; i < n4; i += stride) {
        int c = (i * 4) & 127;
        float4 v = t4[i];
        float4 r;
        r.x = fmaxf(v.x * sc[c]     + sh[c],     0.f);
        r.y = fmaxf(v.y * sc[c + 1] + sh[c + 1], 0.f);
        r.z = fmaxf(v.z * sc[c + 2] + sh[c + 2], 0.f);
        r.w = fmaxf(v.w * sc[c + 3] + sh[c + 3], 0.f);
        if (residual) {
            float4 hv = h4[i];
            r.x += hv.x; r.y += hv.y; r.z += hv.z; r.w += hv.w;
        }
        h4[i] = r;
    }
}

// ---------------------------------------------------------------- CSR build
__global__ void k_deg(const int* __restrict__ dst, int* __restrict__ cnt, int E)
{
    int stride = gridDim.x * blockDim.x;
    for (int e = blockIdx.x * blockDim.x + threadIdx.x; e < E; e += stride)
        atomicAdd(cnt + dst[e], 1);
}

__global__ void k_scan1(const int* __restrict__ cnt, int* __restrict__ rowptr,
                        int* __restrict__ bsum, int N)
{
    __shared__ int sb[256];
    int i = blockIdx.x * 256 + threadIdx.x;
    int v = (i < N) ? cnt[i] : 0;
    sb[threadIdx.x] = v;
    __syncthreads();
    for (int ofs = 1; ofs < 256; ofs <<= 1) {
        int u = (threadIdx.x >= ofs) ? sb[threadIdx.x - ofs] : 0;
        __syncthreads();
        sb[threadIdx.x] += u;
        __syncthreads();
    }
    if (i < N) rowptr[i] = sb[threadIdx.x] - v;
    if (threadIdx.x == 255) bsum[blockIdx.x] = sb[255];
}

__global__ void k_scan2(int* __restrict__ bs, int nb)
{
    __shared__ int sb[512];
    int t = threadIdx.x;
    int v = (t < nb) ? bs[t] : 0;
    sb[t] = v;
    __syncthreads();
    for (int ofs = 1; ofs < 512; ofs <<= 1) {
        int u = (t >= ofs) ? sb[t - ofs] : 0;
        __syncthreads();
        sb[t] += u;
        __syncthreads();
    }
    bs[t] = sb[t] - v;
}

__global__ void k_scan3(int* __restrict__ rowptr, const int* __restrict__ bsum,
                        int N, int E)
{
    int i = blockIdx.x * blockDim.x + threadIdx.x;
    if (i < N) rowptr[i] += bsum[i >> 8];
    if (i == 0) rowptr[N] = E;
}

__global__ void k_scatter(const int* __restrict__ src, const int* __restrict__ dst,
                          const int* __restrict__ rowptr, int* __restrict__ cursor,
                          int* __restrict__ csr, int E)
{
    int stride = gridDim.x * blockDim.x;
    for (int e = blockIdx.x * blockDim.x + threadIdx.x; e < E; e += stride) {
        int d = dst[e];
        int pos = atomicAdd(cursor + d, 1);
        csr[rowptr[d] + pos] = src[e];
    }
}

// ---------------------------------------------------------------- fused GEMM
// basesB[n, 0:64) = bf16(h[n,:] @ bases_w[l]);  combA[n,0:96) = h[n,:] @ comb_w[l] + comb_b
// 8 waves/block; wave w owns 16 consecutive nodes (wave-uniform h rows -> scalar
// loads); lane = output column; W transposed in LDS stride 129 (2 lanes/bank = free).
__global__ __launch_bounds__(512)
void k_gemm160(const float* __restrict__ h, const float* __restrict__ basesW,
               const float* __restrict__ combW, const float* __restrict__ combB,
               unsigned short* __restrict__ basesB, float* __restrict__ combA, int N)
{
    __shared__ float Wt[160 * 129];
    int tid = threadIdx.x;
    for (int i = tid; i < 128 * 64; i += 512) {
        int k = i >> 6, c = i & 63;
        Wt[c * 129 + k] = basesW[i];
    }
    for (int i = tid; i < 128 * 96; i += 512) {
        int k = i / 96, c = i - k * 96;
        Wt[(64 + c) * 129 + k] = combW[i];
    }
    __syncthreads();

    int l = tid & 63;
    int w = __builtin_amdgcn_readfirstlane(tid >> 6);   // force wave-uniform
    int r2 = (l < 32) ? (l + 128) : 159;                // keep LDS reads in bounds
    float b1 = combB[l];
    float b2 = (l < 32) ? combB[64 + l] : 0.f;

    int tileStride = 128 * gridDim.x;
    int trips = (N + tileStride - 1) / tileStride;
    for (int it = 0; it < trips; ++it) {
        int base = (it * gridDim.x + blockIdx.x) * 128 + w * 16;
        int nd[16];
        #pragma unroll
        for (int m = 0; m < 16; ++m) nd[m] = min(base + m, N - 1);

        float acc0[16], acc1[16], acc2[16];
        #pragma unroll
        for (int m = 0; m < 16; ++m) { acc0[m] = 0.f; acc1[m] = 0.f; acc2[m] = 0.f; }

        for (int k = 0; k < 128; k += 4) {
            float4 hv[16];
            #pragma unroll
            for (int m = 0; m < 16; ++m)
                hv[m] = *(const float4*)&h[(size_t)nd[m] * 128 + k];
            #pragma unroll
            for (int kk = 0; kk < 4; ++kk) {
                float w0 = Wt[l * 129 + k + kk];
                float w1 = Wt[(l + 64) * 129 + k + kk];
                float w2 = Wt[r2 * 129 + k + kk];
                #pragma unroll
                for (int m = 0; m < 16; ++m) {
                    float hx = ((const float*)&hv[m])[kk];
                    acc0[m] = fmaf(hx, w0, acc0[m]);
                    acc1[m] = fmaf(hx, w1, acc1[m]);
                    acc2[m] = fmaf(hx, w2, acc2[m]);
                }
            }
        }
        #pragma unroll
        for (int m = 0; m < 16; ++m) {
            int node = base + m;
            if (node < N) {
                basesB[(size_t)node * 64 + l] = f2bf(acc0[m]);
                combA[(size_t)node * 96 + l] = acc1[m] + b1;
                if (l < 32)
                    combA[(size_t)node * 96 + 64 + l] = acc2[m] + b2;
            }
        }
    }
}

// ---------------------------------------------------------------- aggregation
// wave per node, bf16 128B rows, edge loop unrolled x8 for MLP
__global__ __launch_bounds__(256)
void k_agg(const unsigned short* __restrict__ basesB, const float* __restrict__ combA,
           const int* __restrict__ csr, const int* __restrict__ rowptr,
           const float* __restrict__ cbias, float* __restrict__ outb,
           float* __restrict__ stats, int N)
{
    __shared__ float aggL[4][3][64];
    __shared__ float combL[4][96];
    __shared__ float sred[4][256];
    int l = threadIdx.x & 63;
    int w = threadIdx.x >> 6;
    int waveSlots = gridDim.x * 4;
    int trips = (N + waveSlots - 1) / waveSlots;
    float s0 = 0.f, q0 = 0.f, s1 = 0.f, q1 = 0.f;
    for (int it = 0; it < trips; ++it) {
        int n = (it * gridDim.x + blockIdx.x) * 4 + w;
        bool act = n < N;
        if (act) {
            int row0 = rowptr[n], row1 = rowptr[n + 1];
            int cnt = row1 - row0;
            float sv = bf2f(basesB[(size_t)n * 64 + l]);
            float sm = sv, mx = sv;             // self loop
            int j = 0;
            while (j < cnt) {
                int chunk = min(64, cnt - j);
                int idx = (l < chunk) ? csr[row0 + j + l] : 0;
                int tt = 0;
                for (; tt + 8 <= chunk; tt += 8) {
                    int i0 = __shfl(idx, tt,     64);
                    int i1 = __shfl(idx, tt + 1, 64);
                    int i2 = __shfl(idx, tt + 2, 64);
                    int i3 = __shfl(idx, tt + 3, 64);
                    int i4 = __shfl(idx, tt + 4, 64);
                    int i5 = __shfl(idx, tt + 5, 64);
                    int i6 = __shfl(idx, tt + 6, 64);
                    int i7 = __shfl(idx, tt + 7, 64);
                    unsigned short u0 = basesB[(size_t)i0 * 64 + l];
                    unsigned short u1 = basesB[(size_t)i1 * 64 + l];
                    unsigned short u2 = basesB[(size_t)i2 * 64 + l];
                    unsigned short u3 = basesB[(size_t)i3 * 64 + l];
                    unsigned short u4 = basesB[(size_t)i4 * 64 + l];
                    unsigned short u5 = basesB[(size_t)i5 * 64 + l];
                    unsigned short u6 = basesB[(size_t)i6 * 64 + l];
                    unsigned short u7 = basesB[(size_t)i7 * 64 + l];
                    float v0 = bf2f(u0), v1 = bf2f(u1), v2 = bf2f(u2), v3 = bf2f(u3);
                    float v4 = bf2f(u4), v5 = bf2f(u5), v6 = bf2f(u6), v7 = bf2f(u7);
                    sm += ((v0 + v1) + (v2 + v3)) + ((v4 + v5) + (v6 + v7));
                    mx = fmaxf(mx, fmaxf(fmaxf(fmaxf(v0, v1), fmaxf(v2, v3)),
                                         fmaxf(fmaxf(v4, v5), fmaxf(v6, v7))));
                }
                for (; tt < chunk; ++tt) {
                    int sn = __shfl(idx, tt, 64);
                    float v = bf2f(basesB[(size_t)sn * 64 + l]);
                    sm += v;
                    mx = fmaxf(mx, v);
                }
                j += chunk;
            }
            float dg = (float)(cnt + 1);
            aggL[w][0][l] = sm;
            aggL[w][1][l] = sm / dg;
            aggL[w][2][l] = mx;
            combL[w][l] = combA[(size_t)n * 96 + l];
            if (l < 32) combL[w][64 + l] = combA[(size_t)n * 96 + 64 + l];
        }
        __syncthreads();
        if (act) {
            int h0 = l >> 4, f = l & 15;
            float o0 = cbias[l], o1 = cbias[64 + l];
            #pragma unroll
            for (int a = 0; a < 3; ++a) {
                #pragma unroll
                for (int b2 = 0; b2 < 4; ++b2) {
                    float ag = aggL[w][a][b2 * 16 + f];
                    o0 = fmaf(combL[w][h0 * 12 + a * 4 + b2], ag, o0);
                    o1 = fmaf(combL[w][(h0 + 4) * 12 + a * 4 + b2], ag, o1);
                }
            }
            outb[(size_t)n * 128 + l] = o0;
            outb[(size_t)n * 128 + 64 + l] = o1;
            s0 += o0; q0 += o0 * o0; s1 += o1; q1 += o1 * o1;
        }
        __syncthreads();
    }
    sred[0][threadIdx.x] = s0; sred[1][threadIdx.x] = q0;
    sred[2][threadIdx.x] = s1; sred[3][threadIdx.x] = q1;
    __syncthreads();
    if (threadIdx.x < 64) {
        int t = threadIdx.x;
        float v0 = sred[0][t] + sred[0][t + 64] + sred[0][t + 128] + sred[0][t + 192];
        float v1 = sred[1][t] + sred[1][t + 64] + sred[1][t + 128] + sred[1][t + 192];
        float v2 = sred[2][t] + sred[2][t + 64] + sred[2][t + 128] + sred[2][t + 192];
        float v3 = sred[3][t] + sred[3][t + 64] + sred[3][t + 128] + sred[3][t + 192];
        atomicAdd(stats + t, v0);
        atomicAdd(stats + 128 + t, v1);
        atomicAdd(stats + 64 + t, v2);
        atomicAdd(stats + 192 + t, v3);
    }
}

// ---------------------------------------------------------------- pooling
__global__ void k_gbound(const int* __restrict__ batch, int* __restrict__ gstart,
                         int N, int G)
{
    int stride = gridDim.x * blockDim.x;
    for (int n = blockIdx.x * blockDim.x + threadIdx.x; n < N; n += stride) {
        int b = batch[n];
        if (n == 0) {
            for (int g = 0; g <= b; ++g) gstart[g] = 0;
        } else {
            int pb = batch[n - 1];
            for (int g = pb + 1; g <= b; ++g) gstart[g] = n;
        }
        if (n == N - 1) {
            for (int g = b + 1; g <= G; ++g) gstart[g] = N;
        }
    }
}

__global__ void k_gmean(const float* __restrict__ h, const int* __restrict__ gstart,
                        float* __restrict__ gout, int G)
{
    int g = blockIdx.x;
    if (g >= G) return;
    int s = gstart[g], e = gstart[g + 1];
    float acc = 0.f;
    for (int n = s; n < e; ++n) acc += h[(size_t)n * 128 + threadIdx.x];
    float cntf = fmaxf((float)(e - s), 1.f);
    gout[g * 128 + threadIdx.x] = acc / cntf;
}

// ---------------------------------------------------------------- MLP
__global__ void k_mlp1(const float* __restrict__ gin, const float* __restrict__ w1,
                       float* __restrict__ t1, float* __restrict__ stats, int G)
{
    int g = blockIdx.x;
    int c = threadIdx.x;
    const float* gr = gin + g * 128;
    float acc = 0.f;
    for (int k = 0; k < 128; ++k) acc = fmaf(gr[k], w1[k * 64 + c], acc);
    t1[g * 64 + c] = acc;
    atomicAdd(stats + c, acc);
    atomicAdd(stats + 64 + c, acc * acc);
}

__global__ void k_mlp2(const float* __restrict__ t1, const float* __restrict__ stats1,
                       const float* __restrict__ g1, const float* __restrict__ b1,
                       const float* __restrict__ w2, float* __restrict__ t2,
                       float* __restrict__ stats2, float invG, int G)
{
    __shared__ float row[64];
    int g = blockIdx.x;
    int c = threadIdx.x;
    float v = t1[g * 64 + c];
    float mu = stats1[c] * invG;
    float var = stats1[64 + c] * invG - mu * mu;
    row[c] = fmaxf(g1[c] * (v - mu) * rsqrtf(var + EPSV) + b1[c], 0.f);
    __syncthreads();
    if (c < 32) {
        float acc = 0.f;
        #pragma unroll
        for (int k = 0; k < 64; ++k) acc = fmaf(row[k], w2[k * 32 + c], acc);
        t2[g * 32 + c] = acc;
        atomicAdd(stats2 + c, acc);
        atomicAdd(stats2 + 32 + c, acc * acc);
    }
}

__global__ void k_mlp3(const float* __restrict__ t2, const float* __restrict__ stats2,
                       const float* __restrict__ g2, const float* __restrict__ b2,
                       const float* __restrict__ w3, const float* __restrict__ b3,
                       float* __restrict__ out, float invG, int G)
{
    __shared__ float row[32];
    int g = blockIdx.x;
    int c = threadIdx.x;
    if (c < 32) {
        float v = t2[g * 32 + c];
        float mu = stats2[c] * invG;
        float var = stats2[32 + c] * invG - mu * mu;
        row[c] = fmaxf(g2[c] * (v - mu) * rsqrtf(var + EPSV) + b2[c], 0.f);
    }
    __syncthreads();
    if (c < 10) {
        float acc = b3[c];
        #pragma unroll
        for (int k = 0; k < 32; ++k) acc = fmaf(row[k], w3[k * 10 + c], acc);
        out[g * 10 + c] = acc;
    }
}

// ---------------------------------------------------------------- launch
extern "C" void kernel_launch(void* const* d_in, const int* in_sizes, int n_in,
                              void* d_out, int out_size, void* d_ws, size_t ws_size,
                              hipStream_t stream)
{
    const float* x        = (const float*)d_in[0];
    const float* lin1_w   = (const float*)d_in[1];
    const float* lin1_b   = (const float*)d_in[2];
    const float* bn1_g    = (const float*)d_in[3];
    const float* bn1_b    = (const float*)d_in[4];
    const float* bases_w  = (const float*)d_in[5];
    const float* comb_w   = (const float*)d_in[6];
    const float* comb_b   = (const float*)d_in[7];
    const float* conv_bias= (const float*)d_in[8];
    const float* bn_g     = (const float*)d_in[9];
    const float* bn_b     = (const float*)d_in[10];
    const float* mlp_w1   = (const float*)d_in[11];
    const float* mbn1_g   = (const float*)d_in[12];
    const float* mbn1_b   = (const float*)d_in[13];
    const float* mlp_w2   = (const float*)d_in[14];
    const float* mbn2_g   = (const float*)d_in[15];
    const float* mbn2_b   = (const float*)d_in[16];
    const float* mlp_w3   = (const float*)d_in[17];
    const float* mlp_b3   = (const float*)d_in[18];
    const int*   edge_idx = (const int*)d_in[19];
    const int*   batch    = (const int*)d_in[20];
    float* outp = (float*)d_out;

    const int N = in_sizes[20];
    const int E = in_sizes[19] / 2;
    const int G = out_size / 10;
    const int* esrc = edge_idx;
    const int* edst = edge_idx + E;

    char* p = (char*)d_ws;
    auto alloc = [&](size_t bytes) {
        char* r = p;
        p += (bytes + 255) & ~(size_t)255;
        return r;
    };
    float*          h      = (float*)alloc((size_t)N * 128 * 4);
    unsigned short* basesB = (unsigned short*)alloc((size_t)N * 64 * 2);
    float*          combA  = (float*)alloc((size_t)N * 96 * 4);
    float*          outb   = (float*)alloc((size_t)N * 128 * 4);
    int*            csr    = (int*)  alloc((size_t)E * 4);
    int*            rowptr = (int*)  alloc((size_t)(N + 1) * 4);
    float*          tg     = (float*)alloc((size_t)G * 128 * 4);
    float*          t1     = (float*)alloc((size_t)G * 64 * 4);
    float*          t2     = (float*)alloc((size_t)G * 32 * 4);
    int*            gstart = (int*)  alloc((size_t)(G + 1) * 4);
    int*            bsum   = (int*)  alloc(512 * 4);
    char*           zbase  = p;
    int*            cnt    = (int*)  alloc((size_t)N * 4);
    int*            cursor = (int*)  alloc((size_t)N * 4);
    float*          stats  = (float*)alloc(7 * 256 * 4);
    size_t zbytes = (size_t)(p - zbase);
    (void)ws_size; (void)n_in;

    hipMemsetAsync(zbase, 0, zbytes, stream);

    const float invN = 1.0f / (float)N;
    const float invG = 1.0f / (float)G;
    const int nb = (N + 255) / 256;
    const int n4 = N * 32;

    k_lin1<<<1024, 256, 0, stream>>>(x, lin1_w, lin1_b, outb, stats, N);
    k_deg<<<1024, 256, 0, stream>>>(edst, cnt, E);
    k_scan1<<<nb, 256, 0, stream>>>(cnt, rowptr, bsum, N);
    k_scan2<<<1, 512, 0, stream>>>(bsum, nb);
    k_scan3<<<nb, 256, 0, stream>>>(rowptr, bsum, N, E);
    k_scatter<<<1024, 256, 0, stream>>>(esrc, edst, rowptr, cursor, csr, E);
    k_bnapply<<<2048, 256, 0, stream>>>(outb, h, stats, bn1_g, bn1_b, invN, n4, 0);

    for (int l = 0; l < 4; ++l) {
        const float* bw = bases_w + (size_t)l * 128 * 64;
        const float* cw = comb_w + (size_t)l * 128 * 96;
        const float* cb = comb_b + (size_t)l * 96;
        const float* cvb = conv_bias + (size_t)l * 128;
        float* st = stats + (1 + l) * 256;
        k_gemm160<<<256, 512, 0, stream>>>(h, bw, cw, cb, basesB, combA, N);
        k_agg<<<2048, 256, 0, stream>>>(basesB, combA, csr, rowptr, cvb, outb, st, N);
        k_bnapply<<<2048, 256, 0, stream>>>(outb, h, st, bn_g + l * 128, bn_b + l * 128,
                                            invN, n4, 1);
    }

    k_gbound<<<512, 256, 0, stream>>>(batch, gstart, N, G);
    k_gmean<<<G, 128, 0, stream>>>(h, gstart, tg, G);
    float* st5 = stats + 5 * 256;
    float* st6 = stats + 6 * 256;
    k_mlp1<<<G, 64, 0, stream>>>(tg, mlp_w1, t1, st5, G);
    k_mlp2<<<G, 64, 0, stream>>>(t1, st5, mbn1_g, mbn1_b, mlp_w2, t2, st6, invG, G);
    k_mlp3<<<G, 64, 0, stream>>>(t2, st6, mbn2_g, mbn2_b, mlp_w3, mlp_b3, outp, invG, G);
}

// Round 3
// 1069.562 us; speedup vs baseline: 1.8113x; 1.7394x over previous
//
#include <hip/hip_runtime.h>

#define EPSV 1e-5f
#define NEGINF -3.402823466e38f

typedef short bf16x8 __attribute__((ext_vector_type(8)));
typedef float f32x4 __attribute__((ext_vector_type(4)));

__device__ __forceinline__ unsigned short f2bf(float f) {
    union { float f; unsigned i; } c; c.f = f;
    unsigned r = c.i + 0x7fff + ((c.i >> 16) & 1);
    return (unsigned short)(r >> 16);
}
__device__ __forceinline__ float blo(unsigned u) {
    union { unsigned i; float f; } c; c.i = u << 16; return c.f;
}
__device__ __forceinline__ float bhi(unsigned u) {
    union { unsigned i; float f; } c; c.i = u & 0xffff0000u; return c.f;
}

// ---------------------------------------------------------------- lin1 + stats
__global__ void k_lin1(const float* __restrict__ x, const float* __restrict__ w,
                       const float* __restrict__ bvec, float* __restrict__ outb,
                       float* __restrict__ stats, int N)
{
    int l  = threadIdx.x & 63;
    int wv = threadIdx.x >> 6;
    int waveSlots = gridDim.x * 4;
    int trips = (N + waveSlots - 1) / waveSlots;
    float s0 = 0.f, q0 = 0.f, s1 = 0.f, q1 = 0.f;
    for (int it = 0; it < trips; ++it) {
        int n = (it * gridDim.x + blockIdx.x) * 4 + wv;
        if (n < N) {
            const float* xr = x + (size_t)n * 27;
            float a0 = bvec[l], a1 = bvec[64 + l];
            #pragma unroll
            for (int k = 0; k < 27; ++k) {
                float xv = xr[k];
                a0 = fmaf(xv, w[k * 128 + l], a0);
                a1 = fmaf(xv, w[k * 128 + 64 + l], a1);
            }
            outb[(size_t)n * 128 + l] = a0;
            outb[(size_t)n * 128 + 64 + l] = a1;
            s0 += a0; q0 += a0 * a0; s1 += a1; q1 += a1 * a1;
        }
    }
    __shared__ float sred[4][256];
    sred[0][threadIdx.x] = s0; sred[1][threadIdx.x] = q0;
    sred[2][threadIdx.x] = s1; sred[3][threadIdx.x] = q1;
    __syncthreads();
    if (threadIdx.x < 64) {
        int t = threadIdx.x;
        float v0 = sred[0][t] + sred[0][t + 64] + sred[0][t + 128] + sred[0][t + 192];
        float v1 = sred[1][t] + sred[1][t + 64] + sred[1][t + 128] + sred[1][t + 192];
        float v2 = sred[2][t] + sred[2][t + 64] + sred[2][t + 128] + sred[2][t + 192];
        float v3 = sred[3][t] + sred[3][t + 64] + sred[3][t + 128] + sred[3][t + 192];
        atomicAdd(stats + t, v0);
        atomicAdd(stats + 128 + t, v1);
        atomicAdd(stats + 64 + t, v2);
        atomicAdd(stats + 192 + t, v3);
    }
}

// ---------------------------------------------------------------- BN apply (+bf16 copy)
__global__ void k_bnapply(const float* __restrict__ t, float* __restrict__ h,
                          unsigned short* __restrict__ hb,
                          const float* __restrict__ stats,
                          const float* __restrict__ gamma, const float* __restrict__ beta,
                          float invR, int n4, int residual)
{
    __shared__ float sc[128], sh[128];
    if (threadIdx.x < 128) {
        float mu  = stats[threadIdx.x] * invR;
        float var = stats[128 + threadIdx.x] * invR - mu * mu;
        float s   = gamma[threadIdx.x] * rsqrtf(var + EPSV);
        sc[threadIdx.x] = s;
        sh[threadIdx.x] = beta[threadIdx.x] - mu * s;
    }
    __syncthreads();
    const float4* t4 = (const float4*)t;
    float4* h4 = (float4*)h;
    ushort4* hb4 = (ushort4*)hb;
    int stride = gridDim.x * blockDim.x;
    for (int i = blockIdx.x * blockDim.x + threadIdx.x; i < n4; i += stride) {
        int c = (i * 4) & 127;
        float4 v = t4[i];
        float4 r;
        r.x = fmaxf(v.x * sc[c]     + sh[c],     0.f);
        r.y = fmaxf(v.y * sc[c + 1] + sh[c + 1], 0.f);
        r.z = fmaxf(v.z * sc[c + 2] + sh[c + 2], 0.f);
        r.w = fmaxf(v.w * sc[c + 3] + sh[c + 3], 0.f);
        if (residual) {
            float4 hv = h4[i];
            r.x += hv.x; r.y += hv.y; r.z += hv.z; r.w += hv.w;
        }
        h4[i] = r;
        ushort4 rb;
        rb.x = f2bf(r.x); rb.y = f2bf(r.y); rb.z = f2bf(r.z); rb.w = f2bf(r.w);
        hb4[i] = rb;
    }
}

// ---------------------------------------------------------------- CSR build
__global__ void k_deg(const int* __restrict__ dst, int* __restrict__ cnt, int E)
{
    int stride = gridDim.x * blockDim.x;
    for (int e = blockIdx.x * blockDim.x + threadIdx.x; e < E; e += stride)
        atomicAdd(cnt + dst[e], 1);
}

__global__ void k_scan1(const int* __restrict__ cnt, int* __restrict__ rowptr,
                        int* __restrict__ bsum, int N)
{
    __shared__ int sb[256];
    int i = blockIdx.x * 256 + threadIdx.x;
    int v = (i < N) ? cnt[i] : 0;
    sb[threadIdx.x] = v;
    __syncthreads();
    for (int ofs = 1; ofs < 256; ofs <<= 1) {
        int u = (threadIdx.x >= ofs) ? sb[threadIdx.x - ofs] : 0;
        __syncthreads();
        sb[threadIdx.x] += u;
        __syncthreads();
    }
    if (i < N) rowptr[i] = sb[threadIdx.x] - v;
    if (threadIdx.x == 255) bsum[blockIdx.x] = sb[255];
}

__global__ void k_scan2(int* __restrict__ bs, int nb)
{
    __shared__ int sb[512];
    int t = threadIdx.x;
    int v = (t < nb) ? bs[t] : 0;
    sb[t] = v;
    __syncthreads();
    for (int ofs = 1; ofs < 512; ofs <<= 1) {
        int u = (t >= ofs) ? sb[t - ofs] : 0;
        __syncthreads();
        sb[t] += u;
        __syncthreads();
    }
    bs[t] = sb[t] - v;
}

__global__ void k_scan3(int* __restrict__ rowptr, const int* __restrict__ bsum,
                        int N, int E)
{
    int i = blockIdx.x * blockDim.x + threadIdx.x;
    if (i < N) rowptr[i] += bsum[i >> 8];
    if (i == 0) rowptr[N] = E;
}

__global__ void k_scatter(const int* __restrict__ src, const int* __restrict__ dst,
                          const int* __restrict__ rowptr, int* __restrict__ cursor,
                          int* __restrict__ csr, int E)
{
    int stride = gridDim.x * blockDim.x;
    for (int e = blockIdx.x * blockDim.x + threadIdx.x; e < E; e += stride) {
        int d = dst[e];
        int pos = atomicAdd(cursor + d, 1);
        csr[rowptr[d] + pos] = src[e];
    }
}

// ---------------------------------------------------------------- MFMA GEMM
// basesP[n][f][b] (permuted, bf16) = h@bases_w ; combA[n][96] fp32 = h@comb_w + comb_b
// A: m=lane&15, k=quad*8+j ; B: n=lane&15, k=quad*8+j ; C/D: col=lane&15, row=quad*4+reg
__global__ __launch_bounds__(256)
void k_gemm_mfma(const unsigned short* __restrict__ hb, const float* __restrict__ basesW,
                 const float* __restrict__ combW, const float* __restrict__ combB,
                 unsigned short* __restrict__ basesP, float* __restrict__ combA, int N)
{
    __shared__ unsigned short Wlds[2560 * 8];   // [ct*4+ki][lane][8] = 40 KB
    int tid = threadIdx.x;
    for (int i = tid; i < 2560; i += 256) {
        int ct = i >> 8, rem = i & 255;
        int ln = rem & 63;
        int n16 = ln & 15, quad = ln >> 4;
        int k = ((rem >> 6) << 5) + quad * 8;   // ki*32 + quad*8
        unsigned short tmp[8];
        if (ct < 4) {
            int c = ct * 16 + n16;
            #pragma unroll
            for (int j = 0; j < 8; ++j) tmp[j] = f2bf(basesW[(k + j) * 64 + c]);
        } else {
            int c = (ct - 4) * 16 + n16;
            #pragma unroll
            for (int j = 0; j < 8; ++j) tmp[j] = f2bf(combW[(k + j) * 96 + c]);
        }
        uint4 pk;
        pk.x = (unsigned)tmp[0] | ((unsigned)tmp[1] << 16);
        pk.y = (unsigned)tmp[2] | ((unsigned)tmp[3] << 16);
        pk.z = (unsigned)tmp[4] | ((unsigned)tmp[5] << 16);
        pk.w = (unsigned)tmp[6] | ((unsigned)tmp[7] << 16);
        *(uint4*)&Wlds[(size_t)i * 8] = pk;
    }
    __syncthreads();

    int lane = tid & 63, wv = tid >> 6;
    int f = lane & 15, quad = lane >> 4;
    float cbv[6];
    #pragma unroll
    for (int s = 0; s < 6; ++s) cbv[s] = combB[s * 16 + f];

    int tiles = (N + 15) >> 4;
    int waveSlots = gridDim.x * 4;
    for (int tile = blockIdx.x * 4 + wv; tile < tiles; tile += waveSlots) {
        int tb = tile * 16;
        int mnode = min(tb + f, N - 1);
        const unsigned short* arow = hb + (size_t)mnode * 128 + quad * 8;

        f32x4 acc[10];
        #pragma unroll
        for (int ct = 0; ct < 10; ++ct) acc[ct] = (f32x4){0.f, 0.f, 0.f, 0.f};

        #pragma unroll
        for (int ki = 0; ki < 4; ++ki) {
            bf16x8 a = *(const bf16x8*)(arow + ki * 32);
            #pragma unroll
            for (int ct = 0; ct < 10; ++ct) {
                bf16x8 b = *(const bf16x8*)&Wlds[(size_t)((ct * 4 + ki) * 64 + lane) * 8];
                acc[ct] = __builtin_amdgcn_mfma_f32_16x16x32_bf16(a, b, acc[ct], 0, 0, 0);
            }
        }

        #pragma unroll
        for (int r = 0; r < 4; ++r) {
            int node = tb + quad * 4 + r;
            if (node < N) {
                #pragma unroll
                for (int ct = 0; ct < 4; ++ct)
                    basesP[(size_t)node * 64 + f * 4 + ct] = f2bf(acc[ct][r]);
                #pragma unroll
                for (int s = 0; s < 6; ++s)
                    combA[(size_t)node * 96 + s * 16 + f] = acc[4 + s][r] + cbv[s];
            }
        }
    }
}

// ---------------------------------------------------------------- aggregation
// wave/node; lane l: f=l&15 owns basis cols {b*16+f}, sub=l>>4 picks edge in group of 4.
// One uint2 (4 bf16) load per 4 edges. No LDS/barrier in hot loop.
__global__ __launch_bounds__(256)
void k_agg(const uint2* __restrict__ basesP2, const float* __restrict__ combA,
           const int* __restrict__ csr, const int* __restrict__ rowptr,
           const float* __restrict__ cbias, float* __restrict__ outb,
           float* __restrict__ stats, int N)
{
    int l = threadIdx.x & 63;
    int w = threadIdx.x >> 6;
    int f = l & 15, sub = l >> 4;
    int waveSlots = gridDim.x * 4;
    int trips = (N + waveSlots - 1) / waveSlots;
    float s0 = 0.f, q0 = 0.f, s1 = 0.f, q1 = 0.f;

    for (int it = 0; it < trips; ++it) {
        int n = (it * gridDim.x + blockIdx.x) * 4 + w;
        if (n < N) {
            int row0 = rowptr[n], row1 = rowptr[n + 1];
            int cnt = row1 - row0;
            float S0 = 0.f, S1 = 0.f, S2 = 0.f, S3 = 0.f;
            float M0 = NEGINF, M1 = NEGINF, M2 = NEGINF, M3 = NEGINF;
            int j = 0;
            while (j < cnt) {
                int chunk = min(64, cnt - j);
                int idx = (l < chunk) ? csr[row0 + j + l] : 0;
                int full = chunk >> 2;
                int t = 0;
                #pragma unroll 4
                for (; t < full; ++t) {
                    int sn = __shfl(idx, 4 * t + sub, 64);
                    uint2 u = basesP2[(size_t)sn * 16 + f];
                    float v0 = blo(u.x), v1 = bhi(u.x), v2 = blo(u.y), v3 = bhi(u.y);
                    S0 += v0; S1 += v1; S2 += v2; S3 += v3;
                    M0 = fmaxf(M0, v0); M1 = fmaxf(M1, v1);
                    M2 = fmaxf(M2, v2); M3 = fmaxf(M3, v3);
                }
                int nG = (chunk + 3) >> 2;
                for (; t < nG; ++t) {
                    int e = 4 * t + sub;
                    int sn = __shfl(idx, min(e, chunk - 1), 64);
                    uint2 u = basesP2[(size_t)sn * 16 + f];
                    if (e < chunk) {
                        float v0 = blo(u.x), v1 = bhi(u.x), v2 = blo(u.y), v3 = bhi(u.y);
                        S0 += v0; S1 += v1; S2 += v2; S3 += v3;
                        M0 = fmaxf(M0, v0); M1 = fmaxf(M1, v1);
                        M2 = fmaxf(M2, v2); M3 = fmaxf(M3, v3);
                    }
                }
                j += chunk;
            }
            // merge the 4 sub-groups (lanes same f, different sub)
            S0 += __shfl_xor(S0, 16, 64); S1 += __shfl_xor(S1, 16, 64);
            S2 += __shfl_xor(S2, 16, 64); S3 += __shfl_xor(S3, 16, 64);
            S0 += __shfl_xor(S0, 32, 64); S1 += __shfl_xor(S1, 32, 64);
            S2 += __shfl_xor(S2, 32, 64); S3 += __shfl_xor(S3, 32, 64);
            M0 = fmaxf(M0, __shfl_xor(M0, 16, 64)); M1 = fmaxf(M1, __shfl_xor(M1, 16, 64));
            M2 = fmaxf(M2, __shfl_xor(M2, 16, 64)); M3 = fmaxf(M3, __shfl_xor(M3, 16, 64));
            M0 = fmaxf(M0, __shfl_xor(M0, 32, 64)); M1 = fmaxf(M1, __shfl_xor(M1, 32, 64));
            M2 = fmaxf(M2, __shfl_xor(M2, 32, 64)); M3 = fmaxf(M3, __shfl_xor(M3, 32, 64));
            // self loop
            uint2 su = basesP2[(size_t)n * 16 + f];
            float w0 = blo(su.x), w1 = bhi(su.x), w2 = blo(su.y), w3 = bhi(su.y);
            S0 += w0; S1 += w1; S2 += w2; S3 += w3;
            M0 = fmaxf(M0, w0); M1 = fmaxf(M1, w1);
            M2 = fmaxf(M2, w2); M3 = fmaxf(M3, w3);
            float invd = 1.f / (float)(cnt + 1);
            float A0 = S0 * invd, A1 = S1 * invd, A2 = S2 * invd, A3 = S3 * invd;

            const float4* cA = (const float4*)(combA + (size_t)n * 96);
            float4 ca0 = cA[sub * 3], ca1 = cA[sub * 3 + 1], ca2 = cA[sub * 3 + 2];
            float4 cb0 = cA[sub * 3 + 12], cb1 = cA[sub * 3 + 13], cb2 = cA[sub * 3 + 14];

            float o0 = cbias[l], o1 = cbias[64 + l];
            o0 = fmaf(ca0.x, S0, o0); o0 = fmaf(ca0.y, S1, o0);
            o0 = fmaf(ca0.z, S2, o0); o0 = fmaf(ca0.w, S3, o0);
            o0 = fmaf(ca1.x, A0, o0); o0 = fmaf(ca1.y, A1, o0);
            o0 = fmaf(ca1.z, A2, o0); o0 = fmaf(ca1.w, A3, o0);
            o0 = fmaf(ca2.x, M0, o0); o0 = fmaf(ca2.y, M1, o0);
            o0 = fmaf(ca2.z, M2, o0); o0 = fmaf(ca2.w, M3, o0);
            o1 = fmaf(cb0.x, S0, o1); o1 = fmaf(cb0.y, S1, o1);
            o1 = fmaf(cb0.z, S2, o1); o1 = fmaf(cb0.w, S3, o1);
            o1 = fmaf(cb1.x, A0, o1); o1 = fmaf(cb1.y, A1, o1);
            o1 = fmaf(cb1.z, A2, o1); o1 = fmaf(cb1.w, A3, o1);
            o1 = fmaf(cb2.x, M0, o1); o1 = fmaf(cb2.y, M1, o1);
            o1 = fmaf(cb2.z, M2, o1); o1 = fmaf(cb2.w, M3, o1);

            outb[(size_t)n * 128 + l] = o0;
            outb[(size_t)n * 128 + 64 + l] = o1;
            s0 += o0; q0 += o0 * o0; s1 += o1; q1 += o1 * o1;
        }
    }
    __shared__ float sred[4][256];
    sred[0][threadIdx.x] = s0; sred[1][threadIdx.x] = q0;
    sred[2][threadIdx.x] = s1; sred[3][threadIdx.x] = q1;
    __syncthreads();
    if (threadIdx.x < 64) {
        int t = threadIdx.x;
        float v0 = sred[0][t] + sred[0][t + 64] + sred[0][t + 128] + sred[0][t + 192];
        float v1 = sred[1][t] + sred[1][t + 64] + sred[1][t + 128] + sred[1][t + 192];
        float v2 = sred[2][t] + sred[2][t + 64] + sred[2][t + 128] + sred[2][t + 192];
        float v3 = sred[3][t] + sred[3][t + 64] + sred[3][t + 128] + sred[3][t + 192];
        atomicAdd(stats + t, v0);
        atomicAdd(stats + 128 + t, v1);
        atomicAdd(stats + 64 + t, v2);
        atomicAdd(stats + 192 + t, v3);
    }
}

// ---------------------------------------------------------------- pooling
__global__ void k_gbound(const int* __restrict__ batch, int* __restrict__ gstart,
                         int N, int G)
{
    int stride = gridDim.x * blockDim.x;
    for (int n = blockIdx.x * blockDim.x + threadIdx.x; n < N; n += stride) {
        int b = batch[n];
        if (n == 0) {
            for (int g = 0; g <= b; ++g) gstart[g] = 0;
        } else {
            int pb = batch[n - 1];
            for (int g = pb + 1; g <= b; ++g) gstart[g] = n;
        }
        if (n == N - 1) {
            for (int g = b + 1; g <= G; ++g) gstart[g] = N;
        }
    }
}

__global__ void k_gmean(const float* __restrict__ h, const int* __restrict__ gstart,
                        float* __restrict__ gout, int G)
{
    int g = blockIdx.x;
    if (g >= G) return;
    int s = gstart[g], e = gstart[g + 1];
    float acc = 0.f;
    for (int n = s; n < e; ++n) acc += h[(size_t)n * 128 + threadIdx.x];
    float cntf = fmaxf((float)(e - s), 1.f);
    gout[g * 128 + threadIdx.x] = acc / cntf;
}

// ---------------------------------------------------------------- MLP
__global__ void k_mlp1(const float* __restrict__ gin, const float* __restrict__ w1,
                       float* __restrict__ t1, float* __restrict__ stats, int G)
{
    int g = blockIdx.x;
    int c = threadIdx.x;
    const float* gr = gin + g * 128;
    float acc = 0.f;
    for (int k = 0; k < 128; ++k) acc = fmaf(gr[k], w1[k * 64 + c], acc);
    t1[g * 64 + c] = acc;
    atomicAdd(stats + c, acc);
    atomicAdd(stats + 64 + c, acc * acc);
}

__global__ void k_mlp2(const float* __restrict__ t1, const float* __restrict__ stats1,
                       const float* __restrict__ g1, const float* __restrict__ b1,
                       const float* __restrict__ w2, float* __restrict__ t2,
                       float* __restrict__ stats2, float invG, int G)
{
    __shared__ float row[64];
    int g = blockIdx.x;
    int c = threadIdx.x;
    float v = t1[g * 64 + c];
    float mu = stats1[c] * invG;
    float var = stats1[64 + c] * invG - mu * mu;
    row[c] = fmaxf(g1[c] * (v - mu) * rsqrtf(var + EPSV) + b1[c], 0.f);
    __syncthreads();
    if (c < 32) {
        float acc = 0.f;
        #pragma unroll
        for (int k = 0; k < 64; ++k) acc = fmaf(row[k], w2[k * 32 + c], acc);
        t2[g * 32 + c] = acc;
        atomicAdd(stats2 + c, acc);
        atomicAdd(stats2 + 32 + c, acc * acc);
    }
}

__global__ void k_mlp3(const float* __restrict__ t2, const float* __restrict__ stats2,
                       const float* __restrict__ g2, const float* __restrict__ b2,
                       const float* __restrict__ w3, const float* __restrict__ b3,
                       float* __restrict__ out, float invG, int G)
{
    __shared__ float row[32];
    int g = blockIdx.x;
    int c = threadIdx.x;
    if (c < 32) {
        float v = t2[g * 32 + c];
        float mu = stats2[c] * invG;
        float var = stats2[32 + c] * invG - mu * mu;
        row[c] = fmaxf(g2[c] * (v - mu) * rsqrtf(var + EPSV) + b2[c], 0.f);
    }
    __syncthreads();
    if (c < 10) {
        float acc = b3[c];
        #pragma unroll
        for (int k = 0; k < 32; ++k) acc = fmaf(row[k], w3[k * 10 + c], acc);
        out[g * 10 + c] = acc;
    }
}

// ---------------------------------------------------------------- launch
extern "C" void kernel_launch(void* const* d_in, const int* in_sizes, int n_in,
                              void* d_out, int out_size, void* d_ws, size_t ws_size,
                              hipStream_t stream)
{
    const float* x        = (const float*)d_in[0];
    const float* lin1_w   = (const float*)d_in[1];
    const float* lin1_b   = (const float*)d_in[2];
    const float* bn1_g    = (const float*)d_in[3];
    const float* bn1_b    = (const float*)d_in[4];
    const float* bases_w  = (const float*)d_in[5];
    const float* comb_w   = (const float*)d_in[6];
    const float* comb_b   = (const float*)d_in[7];
    const float* conv_bias= (const float*)d_in[8];
    const float* bn_g     = (const float*)d_in[9];
    const float* bn_b     = (const float*)d_in[10];
    const float* mlp_w1   = (const float*)d_in[11];
    const float* mbn1_g   = (const float*)d_in[12];
    const float* mbn1_b   = (const float*)d_in[13];
    const float* mlp_w2   = (const float*)d_in[14];
    const float* mbn2_g   = (const float*)d_in[15];
    const float* mbn2_b   = (const float*)d_in[16];
    const float* mlp_w3   = (const float*)d_in[17];
    const float* mlp_b3   = (const float*)d_in[18];
    const int*   edge_idx = (const int*)d_in[19];
    const int*   batch    = (const int*)d_in[20];
    float* outp = (float*)d_out;

    const int N = in_sizes[20];
    const int E = in_sizes[19] / 2;
    const int G = out_size / 10;
    const int* esrc = edge_idx;
    const int* edst = edge_idx + E;

    char* p = (char*)d_ws;
    auto alloc = [&](size_t bytes) {
        char* r = p;
        p += (bytes + 255) & ~(size_t)255;
        return r;
    };
    float*          h      = (float*)alloc((size_t)N * 128 * 4);
    unsigned short* hb     = (unsigned short*)alloc((size_t)N * 128 * 2);
    unsigned short* basesP = (unsigned short*)alloc((size_t)N * 64 * 2);
    float*          combA  = (float*)alloc((size_t)N * 96 * 4);
    float*          outb   = (float*)alloc((size_t)N * 128 * 4);
    int*            csr    = (int*)  alloc((size_t)E * 4);
    int*            rowptr = (int*)  alloc((size_t)(N + 1) * 4);
    float*          tg     = (float*)alloc((size_t)G * 128 * 4);
    float*          t1     = (float*)alloc((size_t)G * 64 * 4);
    float*          t2     = (float*)alloc((size_t)G * 32 * 4);
    int*            gstart = (int*)  alloc((size_t)(G + 1) * 4);
    int*            bsum   = (int*)  alloc(512 * 4);
    char*           zbase  = p;
    int*            cnt    = (int*)  alloc((size_t)N * 4);
    int*            cursor = (int*)  alloc((size_t)N * 4);
    float*          stats  = (float*)alloc(7 * 256 * 4);
    size_t zbytes = (size_t)(p - zbase);
    (void)ws_size; (void)n_in;

    hipMemsetAsync(zbase, 0, zbytes, stream);

    const float invN = 1.0f / (float)N;
    const float invG = 1.0f / (float)G;
    const int nb = (N + 255) / 256;
    const int n4 = N * 32;

    k_lin1<<<1024, 256, 0, stream>>>(x, lin1_w, lin1_b, outb, stats, N);
    k_deg<<<1024, 256, 0, stream>>>(edst, cnt, E);
    k_scan1<<<nb, 256, 0, stream>>>(cnt, rowptr, bsum, N);
    k_scan2<<<1, 512, 0, stream>>>(bsum, nb);
    k_scan3<<<nb, 256, 0, stream>>>(rowptr, bsum, N, E);
    k_scatter<<<1024, 256, 0, stream>>>(esrc, edst, rowptr, cursor, csr, E);
    k_bnapply<<<2048, 256, 0, stream>>>(outb, h, hb, stats, bn1_g, bn1_b, invN, n4, 0);

    for (int l = 0; l < 4; ++l) {
        const float* bw = bases_w + (size_t)l * 128 * 64;
        const float* cw = comb_w + (size_t)l * 128 * 96;
        const float* cb = comb_b + (size_t)l * 96;
        const float* cvb = conv_bias + (size_t)l * 128;
        float* st = stats + (1 + l) * 256;
        k_gemm_mfma<<<512, 256, 0, stream>>>(hb, bw, cw, cb, basesP, combA, N);
        k_agg<<<2048, 256, 0, stream>>>((const uint2*)basesP, combA, csr, rowptr, cvb,
                                        outb, st, N);
        k_bnapply<<<2048, 256, 0, stream>>>(outb, h, hb, st, bn_g + l * 128,
                                            bn_b + l * 128, invN, n4, 1);
    }

    k_gbound<<<512, 256, 0, stream>>>(batch, gstart, N, G);
    k_gmean<<<G, 128, 0, stream>>>(h, gstart, tg, G);
    float* st5 = stats + 5 * 256;
    float* st6 = stats + 6 * 256;
    k_mlp1<<<G, 64, 0, stream>>>(tg, mlp_w1, t1, st5, G);
    k_mlp2<<<G, 64, 0, stream>>>(t1, st5, mbn1_g, mbn1_b, mlp_w2, t2, st6, invG, G);
    k_mlp3<<<G, 64, 0, stream>>>(t2, st6, mbn2_g, mbn2_b, mlp_w3, mlp_b3, outp, invG, G);
}

// Round 4
// 863.952 us; speedup vs baseline: 2.2424x; 1.2380x over previous
//
#include <hip/hip_runtime.h>

#define EPSV 1e-5f
#define NEGINF -3.402823466e38f
#define NBMAX 1600
#define CHUNK 8192
#define CAP3 6144

typedef short bf16x8 __attribute__((ext_vector_type(8)));
typedef float f32x4 __attribute__((ext_vector_type(4)));

__device__ __forceinline__ unsigned short f2bf(float f) {
    union { float f; unsigned i; } c; c.f = f;
    unsigned r = c.i + 0x7fff + ((c.i >> 16) & 1);
    return (unsigned short)(r >> 16);
}
__device__ __forceinline__ float blo(unsigned u) {
    union { unsigned i; float f; } c; c.i = u << 16; return c.f;
}
__device__ __forceinline__ float bhi(unsigned u) {
    union { unsigned i; float f; } c; c.i = u & 0xffff0000u; return c.f;
}

// ---------------------------------------------------------------- lin1 + stats
__global__ void k_lin1(const float* __restrict__ x, const float* __restrict__ w,
                       const float* __restrict__ bvec, float* __restrict__ outb,
                       float* __restrict__ stats, int N)
{
    int l  = threadIdx.x & 63;
    int wv = threadIdx.x >> 6;
    int waveSlots = gridDim.x * 4;
    int trips = (N + waveSlots - 1) / waveSlots;
    float s0 = 0.f, q0 = 0.f, s1 = 0.f, q1 = 0.f;
    for (int it = 0; it < trips; ++it) {
        int n = (it * gridDim.x + blockIdx.x) * 4 + wv;
        if (n < N) {
            const float* xr = x + (size_t)n * 27;
            float a0 = bvec[l], a1 = bvec[64 + l];
            #pragma unroll
            for (int k = 0; k < 27; ++k) {
                float xv = xr[k];
                a0 = fmaf(xv, w[k * 128 + l], a0);
                a1 = fmaf(xv, w[k * 128 + 64 + l], a1);
            }
            outb[(size_t)n * 128 + l] = a0;
            outb[(size_t)n * 128 + 64 + l] = a1;
            s0 += a0; q0 += a0 * a0; s1 += a1; q1 += a1 * a1;
        }
    }
    __shared__ float sred[4][256];
    sred[0][threadIdx.x] = s0; sred[1][threadIdx.x] = q0;
    sred[2][threadIdx.x] = s1; sred[3][threadIdx.x] = q1;
    __syncthreads();
    if (threadIdx.x < 64) {
        int t = threadIdx.x;
        float v0 = sred[0][t] + sred[0][t + 64] + sred[0][t + 128] + sred[0][t + 192];
        float v1 = sred[1][t] + sred[1][t + 64] + sred[1][t + 128] + sred[1][t + 192];
        float v2 = sred[2][t] + sred[2][t + 64] + sred[2][t + 128] + sred[2][t + 192];
        float v3 = sred[3][t] + sred[3][t + 64] + sred[3][t + 128] + sred[3][t + 192];
        atomicAdd(stats + t, v0);
        atomicAdd(stats + 128 + t, v1);
        atomicAdd(stats + 64 + t, v2);
        atomicAdd(stats + 192 + t, v3);
    }
}

// ---------------------------------------------------------------- bucketed CSR build
__global__ __launch_bounds__(256)
void k_p1_hist(const int* __restrict__ dst, int* __restrict__ bcnt,
               int E, int NB, int shift)
{
    __shared__ int hist[NBMAX];
    for (int i = threadIdx.x; i < NB; i += 256) hist[i] = 0;
    __syncthreads();
    int stride = gridDim.x * 256;
    for (int e = blockIdx.x * 256 + threadIdx.x; e < E; e += stride)
        atomicAdd(&hist[dst[e] >> shift], 1);
    __syncthreads();
    for (int i = threadIdx.x; i < NB; i += 256)
        if (hist[i]) atomicAdd(bcnt + i, hist[i]);
}

__global__ void k_scan1(const int* __restrict__ cnt, int* __restrict__ rowptr,
                        int* __restrict__ bsum, int N)
{
    __shared__ int sb[256];
    int i = blockIdx.x * 256 + threadIdx.x;
    int v = (i < N) ? cnt[i] : 0;
    sb[threadIdx.x] = v;
    __syncthreads();
    for (int ofs = 1; ofs < 256; ofs <<= 1) {
        int u = (threadIdx.x >= ofs) ? sb[threadIdx.x - ofs] : 0;
        __syncthreads();
        sb[threadIdx.x] += u;
        __syncthreads();
    }
    if (i < N) rowptr[i] = sb[threadIdx.x] - v;
    if (threadIdx.x == 255) bsum[blockIdx.x] = sb[255];
}

__global__ void k_scan2(int* __restrict__ bs, int nb)
{
    __shared__ int sb[512];
    int t = threadIdx.x;
    int v = (t < nb) ? bs[t] : 0;
    sb[t] = v;
    __syncthreads();
    for (int ofs = 1; ofs < 512; ofs <<= 1) {
        int u = (t >= ofs) ? sb[t - ofs] : 0;
        __syncthreads();
        sb[t] += u;
        __syncthreads();
    }
    bs[t] = sb[t] - v;
}

__global__ void k_scan3(int* __restrict__ rowptr, const int* __restrict__ bsum,
                        int N, int E)
{
    int i = blockIdx.x * blockDim.x + threadIdx.x;
    if (i < N) rowptr[i] += bsum[i >> 8];
    if (i == 0) rowptr[N] = E;
}

// stage CHUNK edges in LDS, bucket-sort locally, copy out run-wise (coalesced)
__global__ __launch_bounds__(256)
void k_p2_scatter(const int* __restrict__ src, const int* __restrict__ dst,
                  const int* __restrict__ bbase, int* __restrict__ bcur0,
                  uint2* __restrict__ bucketed, int E, int NB, int shift)
{
    __shared__ uint2 ebuf[CHUNK];
    __shared__ int hist[NBMAX];
    __shared__ int cur[NBMAX];
    __shared__ int wtmp[256];
    int tid = threadIdx.x;
    int c0 = blockIdx.x * CHUNK;
    int cc = min(CHUNK, E - c0);
    if (cc <= 0) return;

    for (int i = tid; i < NB; i += 256) hist[i] = 0;
    __syncthreads();
    for (int i = tid; i < cc; i += 256)
        atomicAdd(&hist[dst[c0 + i] >> shift], 1);
    __syncthreads();
    // block-exclusive-scan hist -> cur
    int per = (NB + 255) / 256;
    int beg = tid * per, end = min(beg + per, NB);
    int s = 0;
    for (int i = beg; i < end; ++i) s += hist[i];
    wtmp[tid] = s;
    __syncthreads();
    for (int ofs = 1; ofs < 256; ofs <<= 1) {
        int u = (tid >= ofs) ? wtmp[tid - ofs] : 0;
        __syncthreads();
        wtmp[tid] += u;
        __syncthreads();
    }
    int run = wtmp[tid] - s;
    for (int i = beg; i < end; ++i) { cur[i] = run; run += hist[i]; }
    __syncthreads();
    // local scatter into LDS
    for (int i = tid; i < cc; i += 256) {
        int sv = src[c0 + i], dv = dst[c0 + i];
        int b = dv >> shift;
        int pos = atomicAdd(&cur[b], 1);
        ebuf[pos] = make_uint2((unsigned)sv, (unsigned)dv);
    }
    __syncthreads();
    // reserve global runs; hist[b] := global_base - local_base
    for (int b = tid; b < NB; b += 256) {
        int c = hist[b];
        if (c > 0) {
            int lb = cur[b] - c;
            int gb = bbase[b] + atomicAdd(&bcur0[b], c);
            hist[b] = gb - lb;
        }
    }
    __syncthreads();
    // run-wise copy out (consecutive i in same bucket -> consecutive slots)
    for (int i = tid; i < cc; i += 256) {
        uint2 u = ebuf[i];
        int b = (int)(u.y >> shift);
        bucketed[hist[b] + i] = u;
    }
}

// one block per bucket: build rowptr + csr for <=128 nodes
__global__ __launch_bounds__(256)
void k_p3_csr(const uint2* __restrict__ bucketed, const int* __restrict__ bbase,
              int* __restrict__ rowptr, int* __restrict__ csr,
              int N, int NB, int shift)
{
    __shared__ int ncnt[128], nsc[128];
    __shared__ int lcsr[CAP3];
    int b = blockIdx.x;
    int tid = threadIdx.x;
    int e0 = bbase[b], e1 = bbase[b + 1];
    int cnt = e1 - e0;
    int node0 = b << shift;
    int nodes = min(1 << shift, N - node0);

    if (tid < 128) ncnt[tid] = 0;
    __syncthreads();
    for (int i = tid; i < cnt; i += 256)
        atomicAdd(&ncnt[(int)bucketed[e0 + i].y - node0], 1);
    __syncthreads();
    if (tid < 128) nsc[tid] = ncnt[tid];
    __syncthreads();
    for (int ofs = 1; ofs < 128; ofs <<= 1) {
        int u = 0;
        if (tid < 128 && tid >= ofs) u = nsc[tid - ofs];
        __syncthreads();
        if (tid < 128) nsc[tid] += u;
        __syncthreads();
    }
    if (tid < nodes) rowptr[node0 + tid] = e0 + nsc[tid] - ncnt[tid];
    if (tid == 0 && b == NB - 1) rowptr[N] = e1;
    if (tid < 128) ncnt[tid] = nsc[tid] - ncnt[tid];   // cursor = exclusive base
    __syncthreads();
    if (cnt <= CAP3) {
        for (int i = tid; i < cnt; i += 256) {
            uint2 u = bucketed[e0 + i];
            int d = (int)u.y - node0;
            int pos = atomicAdd(&ncnt[d], 1);
            lcsr[pos] = (int)u.x;
        }
        __syncthreads();
        for (int i = tid; i < cnt; i += 256) csr[e0 + i] = lcsr[i];
    } else {
        for (int i = tid; i < cnt; i += 256) {
            uint2 u = bucketed[e0 + i];
            int d = (int)u.y - node0;
            int pos = atomicAdd(&ncnt[d], 1);
            csr[e0 + pos] = (int)u.x;
        }
    }
}

// ---------------------------------------------------------------- fused BN + MFMA GEMM
// h_new = (res? h:0) + relu(bn(tin)); basesP = bf16(h_new@basesW); combB16 = bf16(h_new@combW + cb)
__global__ __launch_bounds__(256)
void k_gemm_mfma(const float* __restrict__ tin, float* __restrict__ h,
                 const float* __restrict__ stats, const float* __restrict__ gamma,
                 const float* __restrict__ beta, float invN, int residual,
                 const float* __restrict__ basesW, const float* __restrict__ combW,
                 const float* __restrict__ combB,
                 unsigned short* __restrict__ basesP,
                 unsigned short* __restrict__ combB16, int N)
{
    __shared__ unsigned short Wlds[2560 * 8];   // 40 KB
    __shared__ float scL[128], shL[128];
    int tid = threadIdx.x;
    if (tid < 128) {
        float mu  = stats[tid] * invN;
        float var = stats[128 + tid] * invN - mu * mu;
        float sc  = gamma[tid] * rsqrtf(var + EPSV);
        scL[tid] = sc;
        shL[tid] = beta[tid] - mu * sc;
    }
    for (int i = tid; i < 2560; i += 256) {
        int ct = i >> 8, rem = i & 255;
        int ln = rem & 63;
        int n16 = ln & 15, quad = ln >> 4;
        int k = ((rem >> 6) << 5) + quad * 8;
        unsigned short tmp[8];
        if (ct < 4) {
            int c = ct * 16 + n16;
            #pragma unroll
            for (int j = 0; j < 8; ++j) tmp[j] = f2bf(basesW[(k + j) * 64 + c]);
        } else {
            int c = (ct - 4) * 16 + n16;
            #pragma unroll
            for (int j = 0; j < 8; ++j) tmp[j] = f2bf(combW[(k + j) * 96 + c]);
        }
        uint4 pk;
        pk.x = (unsigned)tmp[0] | ((unsigned)tmp[1] << 16);
        pk.y = (unsigned)tmp[2] | ((unsigned)tmp[3] << 16);
        pk.z = (unsigned)tmp[4] | ((unsigned)tmp[5] << 16);
        pk.w = (unsigned)tmp[6] | ((unsigned)tmp[7] << 16);
        *(uint4*)&Wlds[(size_t)i * 8] = pk;
    }
    __syncthreads();

    int lane = tid & 63, wv = tid >> 6;
    int f = lane & 15, quad = lane >> 4;
    float cbv[6];
    #pragma unroll
    for (int s = 0; s < 6; ++s) cbv[s] = combB[s * 16 + f];

    int tiles = (N + 15) >> 4;
    int waveSlots = gridDim.x * 4;
    for (int tile = blockIdx.x * 4 + wv; tile < tiles; tile += waveSlots) {
        int tb = tile * 16;
        int mnode = min(tb + f, N - 1);
        size_t rbase = (size_t)mnode * 128;

        f32x4 acc[10];
        #pragma unroll
        for (int ct = 0; ct < 10; ++ct) acc[ct] = (f32x4){0.f, 0.f, 0.f, 0.f};

        #pragma unroll
        for (int ki = 0; ki < 4; ++ki) {
            int kc = quad * 8 + ki * 32;
            float4 t0 = *(const float4*)&tin[rbase + kc];
            float4 t1 = *(const float4*)&tin[rbase + kc + 4];
            float4 r0, r1;
            r0.x = fmaxf(t0.x * scL[kc]     + shL[kc],     0.f);
            r0.y = fmaxf(t0.y * scL[kc + 1] + shL[kc + 1], 0.f);
            r0.z = fmaxf(t0.z * scL[kc + 2] + shL[kc + 2], 0.f);
            r0.w = fmaxf(t0.w * scL[kc + 3] + shL[kc + 3], 0.f);
            r1.x = fmaxf(t1.x * scL[kc + 4] + shL[kc + 4], 0.f);
            r1.y = fmaxf(t1.y * scL[kc + 5] + shL[kc + 5], 0.f);
            r1.z = fmaxf(t1.z * scL[kc + 6] + shL[kc + 6], 0.f);
            r1.w = fmaxf(t1.w * scL[kc + 7] + shL[kc + 7], 0.f);
            if (residual) {
                float4 h0 = *(const float4*)&h[rbase + kc];
                float4 h1 = *(const float4*)&h[rbase + kc + 4];
                r0.x += h0.x; r0.y += h0.y; r0.z += h0.z; r0.w += h0.w;
                r1.x += h1.x; r1.y += h1.y; r1.z += h1.z; r1.w += h1.w;
            }
            *(float4*)&h[rbase + kc] = r0;
            *(float4*)&h[rbase + kc + 4] = r1;
            short ab[8];
            ab[0] = (short)f2bf(r0.x); ab[1] = (short)f2bf(r0.y);
            ab[2] = (short)f2bf(r0.z); ab[3] = (short)f2bf(r0.w);
            ab[4] = (short)f2bf(r1.x); ab[5] = (short)f2bf(r1.y);
            ab[6] = (short)f2bf(r1.z); ab[7] = (short)f2bf(r1.w);
            bf16x8 a = *(bf16x8*)ab;
            #pragma unroll
            for (int ct = 0; ct < 10; ++ct) {
                bf16x8 bfr = *(const bf16x8*)&Wlds[(size_t)((ct * 4 + ki) * 64 + lane) * 8];
                acc[ct] = __builtin_amdgcn_mfma_f32_16x16x32_bf16(a, bfr, acc[ct], 0, 0, 0);
            }
        }

        #pragma unroll
        for (int r = 0; r < 4; ++r) {
            int node = tb + quad * 4 + r;
            if (node < N) {
                #pragma unroll
                for (int ct = 0; ct < 4; ++ct)
                    basesP[(size_t)node * 64 + f * 4 + ct] = f2bf(acc[ct][r]);
                #pragma unroll
                for (int s = 0; s < 6; ++s)
                    combB16[(size_t)node * 96 + s * 16 + f] = f2bf(acc[4 + s][r] + cbv[s]);
            }
        }
    }
}

// ---------------------------------------------------------------- aggregation
__global__ __launch_bounds__(256)
void k_agg(const uint2* __restrict__ basesP2, const unsigned short* __restrict__ combB16,
           const int* __restrict__ csr, const int* __restrict__ rowptr,
           const float* __restrict__ cbias, float* __restrict__ outb,
           float* __restrict__ stats, int N)
{
    int l = threadIdx.x & 63;
    int w = threadIdx.x >> 6;
    int f = l & 15, sub = l >> 4;
    int waveSlots = gridDim.x * 4;
    int trips = (N + waveSlots - 1) / waveSlots;
    float s0 = 0.f, q0 = 0.f, s1 = 0.f, q1 = 0.f;

    for (int it = 0; it < trips; ++it) {
        int n = (it * gridDim.x + blockIdx.x) * 4 + w;
        if (n < N) {
            int row0 = rowptr[n], row1 = rowptr[n + 1];
            int cnt = row1 - row0;
            float S0 = 0.f, S1 = 0.f, S2 = 0.f, S3 = 0.f;
            float M0 = NEGINF, M1 = NEGINF, M2 = NEGINF, M3 = NEGINF;
            int j = 0;
            while (j < cnt) {
                int chunk = min(64, cnt - j);
                int idx = (l < chunk) ? csr[row0 + j + l] : 0;
                int full = chunk >> 2;
                int t = 0;
                #pragma unroll 4
                for (; t < full; ++t) {
                    int sn = __shfl(idx, 4 * t + sub, 64);
                    uint2 u = basesP2[(size_t)sn * 16 + f];
                    float v0 = blo(u.x), v1 = bhi(u.x), v2 = blo(u.y), v3 = bhi(u.y);
                    S0 += v0; S1 += v1; S2 += v2; S3 += v3;
                    M0 = fmaxf(M0, v0); M1 = fmaxf(M1, v1);
                    M2 = fmaxf(M2, v2); M3 = fmaxf(M3, v3);
                }
                int nG = (chunk + 3) >> 2;
                for (; t < nG; ++t) {
                    int e = 4 * t + sub;
                    int sn = __shfl(idx, min(e, chunk - 1), 64);
                    uint2 u = basesP2[(size_t)sn * 16 + f];
                    if (e < chunk) {
                        float v0 = blo(u.x), v1 = bhi(u.x), v2 = blo(u.y), v3 = bhi(u.y);
                        S0 += v0; S1 += v1; S2 += v2; S3 += v3;
                        M0 = fmaxf(M0, v0); M1 = fmaxf(M1, v1);
                        M2 = fmaxf(M2, v2); M3 = fmaxf(M3, v3);
                    }
                }
                j += chunk;
            }
            S0 += __shfl_xor(S0, 16, 64); S1 += __shfl_xor(S1, 16, 64);
            S2 += __shfl_xor(S2, 16, 64); S3 += __shfl_xor(S3, 16, 64);
            S0 += __shfl_xor(S0, 32, 64); S1 += __shfl_xor(S1, 32, 64);
            S2 += __shfl_xor(S2, 32, 64); S3 += __shfl_xor(S3, 32, 64);
            M0 = fmaxf(M0, __shfl_xor(M0, 16, 64)); M1 = fmaxf(M1, __shfl_xor(M1, 16, 64));
            M2 = fmaxf(M2, __shfl_xor(M2, 16, 64)); M3 = fmaxf(M3, __shfl_xor(M3, 16, 64));
            M0 = fmaxf(M0, __shfl_xor(M0, 32, 64)); M1 = fmaxf(M1, __shfl_xor(M1, 32, 64));
            M2 = fmaxf(M2, __shfl_xor(M2, 32, 64)); M3 = fmaxf(M3, __shfl_xor(M3, 32, 64));
            uint2 su = basesP2[(size_t)n * 16 + f];
            float w0 = blo(su.x), w1 = bhi(su.x), w2 = blo(su.y), w3 = bhi(su.y);
            S0 += w0; S1 += w1; S2 += w2; S3 += w3;
            M0 = fmaxf(M0, w0); M1 = fmaxf(M1, w1);
            M2 = fmaxf(M2, w2); M3 = fmaxf(M3, w3);
            float invd = 1.f / (float)(cnt + 1);
            float A0 = S0 * invd, A1 = S1 * invd, A2 = S2 * invd, A3 = S3 * invd;

            const unsigned short* cr = combB16 + (size_t)n * 96;
            const uint2* c0p = (const uint2*)(cr + sub * 12);
            const uint2* c1p = (const uint2*)(cr + 48 + sub * 12);
            uint2 qa0 = c0p[0], qa1 = c0p[1], qa2 = c0p[2];
            uint2 qb0 = c1p[0], qb1 = c1p[1], qb2 = c1p[2];

            float o0 = cbias[l], o1 = cbias[64 + l];
            o0 = fmaf(blo(qa0.x), S0, o0); o0 = fmaf(bhi(qa0.x), S1, o0);
            o0 = fmaf(blo(qa0.y), S2, o0); o0 = fmaf(bhi(qa0.y), S3, o0);
            o0 = fmaf(blo(qa1.x), A0, o0); o0 = fmaf(bhi(qa1.x), A1, o0);
            o0 = fmaf(blo(qa1.y), A2, o0); o0 = fmaf(bhi(qa1.y), A3, o0);
            o0 = fmaf(blo(qa2.x), M0, o0); o0 = fmaf(bhi(qa2.x), M1, o0);
            o0 = fmaf(blo(qa2.y), M2, o0); o0 = fmaf(bhi(qa2.y), M3, o0);
            o1 = fmaf(blo(qb0.x), S0, o1); o1 = fmaf(bhi(qb0.x), S1, o1);
            o1 = fmaf(blo(qb0.y), S2, o1); o1 = fmaf(bhi(qb0.y), S3, o1);
            o1 = fmaf(blo(qb1.x), A0, o1); o1 = fmaf(bhi(qb1.x), A1, o1);
            o1 = fmaf(blo(qb1.y), A2, o1); o1 = fmaf(bhi(qb1.y), A3, o1);
            o1 = fmaf(blo(qb2.x), M0, o1); o1 = fmaf(bhi(qb2.x), M1, o1);
            o1 = fmaf(blo(qb2.y), M2, o1); o1 = fmaf(bhi(qb2.y), M3, o1);

            outb[(size_t)n * 128 + l] = o0;
            outb[(size_t)n * 128 + 64 + l] = o1;
            s0 += o0; q0 += o0 * o0; s1 += o1; q1 += o1 * o1;
        }
    }
    __shared__ float sred[4][256];
    sred[0][threadIdx.x] = s0; sred[1][threadIdx.x] = q0;
    sred[2][threadIdx.x] = s1; sred[3][threadIdx.x] = q1;
    __syncthreads();
    if (threadIdx.x < 64) {
        int t = threadIdx.x;
        float v0 = sred[0][t] + sred[0][t + 64] + sred[0][t + 128] + sred[0][t + 192];
        float v1 = sred[1][t] + sred[1][t + 64] + sred[1][t + 128] + sred[1][t + 192];
        float v2 = sred[2][t] + sred[2][t + 64] + sred[2][t + 128] + sred[2][t + 192];
        float v3 = sred[3][t] + sred[3][t + 64] + sred[3][t + 128] + sred[3][t + 192];
        atomicAdd(stats + t, v0);
        atomicAdd(stats + 128 + t, v1);
        atomicAdd(stats + 64 + t, v2);
        atomicAdd(stats + 192 + t, v3);
    }
}

// ---------------------------------------------------------------- pooling (fused final BN)
__global__ void k_gbound(const int* __restrict__ batch, int* __restrict__ gstart,
                         int N, int G)
{
    int stride = gridDim.x * blockDim.x;
    for (int n = blockIdx.x * blockDim.x + threadIdx.x; n < N; n += stride) {
        int b = batch[n];
        if (n == 0) {
            for (int g = 0; g <= b; ++g) gstart[g] = 0;
        } else {
            int pb = batch[n - 1];
            for (int g = pb + 1; g <= b; ++g) gstart[g] = n;
        }
        if (n == N - 1) {
            for (int g = b + 1; g <= G; ++g) gstart[g] = N;
        }
    }
}

__global__ void k_gmean(const float* __restrict__ t, const float* __restrict__ h,
                        const float* __restrict__ stats, const float* __restrict__ gamma,
                        const float* __restrict__ beta, float invN,
                        const int* __restrict__ gstart, float* __restrict__ gout, int G)
{
    int g = blockIdx.x;
    if (g >= G) return;
    int c = threadIdx.x;
    float mu  = stats[c] * invN;
    float var = stats[128 + c] * invN - mu * mu;
    float sc  = gamma[c] * rsqrtf(var + EPSV);
    float sh  = beta[c] - mu * sc;
    int s = gstart[g], e = gstart[g + 1];
    float acc = 0.f;
    for (int n = s; n < e; ++n) {
        size_t o = (size_t)n * 128 + c;
        acc += h[o] + fmaxf(t[o] * sc + sh, 0.f);
    }
    float cntf = fmaxf((float)(e - s), 1.f);
    gout[g * 128 + c] = acc / cntf;
}

// ---------------------------------------------------------------- MLP
__global__ void k_mlp1(const float* __restrict__ gin, const float* __restrict__ w1,
                       float* __restrict__ t1, float* __restrict__ stats, int G)
{
    int g = blockIdx.x;
    int c = threadIdx.x;
    const float* gr = gin + g * 128;
    float acc = 0.f;
    for (int k = 0; k < 128; ++k) acc = fmaf(gr[k], w1[k * 64 + c], acc);
    t1[g * 64 + c] = acc;
    atomicAdd(stats + c, acc);
    atomicAdd(stats + 64 + c, acc * acc);
}

__global__ void k_mlp2(const float* __restrict__ t1, const float* __restrict__ stats1,
                       const float* __restrict__ g1, const float* __restrict__ b1,
                       const float* __restrict__ w2, float* __restrict__ t2,
                       float* __restrict__ stats2, float invG, int G)
{
    __shared__ float row[64];
    int g = blockIdx.x;
    int c = threadIdx.x;
    float v = t1[g * 64 + c];
    float mu = stats1[c] * invG;
    float var = stats1[64 + c] * invG - mu * mu;
    row[c] = fmaxf(g1[c] * (v - mu) * rsqrtf(var + EPSV) + b1[c], 0.f);
    __syncthreads();
    if (c < 32) {
        float acc = 0.f;
        #pragma unroll
        for (int k = 0; k < 64; ++k) acc = fmaf(row[k], w2[k * 32 + c], acc);
        t2[g * 32 + c] = acc;
        atomicAdd(stats2 + c, acc);
        atomicAdd(stats2 + 32 + c, acc * acc);
    }
}

__global__ void k_mlp3(const float* __restrict__ t2, const float* __restrict__ stats2,
                       const float* __restrict__ g2, const float* __restrict__ b2,
                       const float* __restrict__ w3, const float* __restrict__ b3,
                       float* __restrict__ out, float invG, int G)
{
    __shared__ float row[32];
    int g = blockIdx.x;
    int c = threadIdx.x;
    if (c < 32) {
        float v = t2[g * 32 + c];
        float mu = stats2[c] * invG;
        float var = stats2[32 + c] * invG - mu * mu;
        row[c] = fmaxf(g2[c] * (v - mu) * rsqrtf(var + EPSV) + b2[c], 0.f);
    }
    __syncthreads();
    if (c < 10) {
        float acc = b3[c];
        #pragma unroll
        for (int k = 0; k < 32; ++k) acc = fmaf(row[k], w3[k * 10 + c], acc);
        out[g * 10 + c] = acc;
    }
}

// ---------------------------------------------------------------- launch
extern "C" void kernel_launch(void* const* d_in, const int* in_sizes, int n_in,
                              void* d_out, int out_size, void* d_ws, size_t ws_size,
                              hipStream_t stream)
{
    const float* x        = (const float*)d_in[0];
    const float* lin1_w   = (const float*)d_in[1];
    const float* lin1_b   = (const float*)d_in[2];
    const float* bn1_g    = (const float*)d_in[3];
    const float* bn1_b    = (const float*)d_in[4];
    const float* bases_w  = (const float*)d_in[5];
    const float* comb_w   = (const float*)d_in[6];
    const float* comb_b   = (const float*)d_in[7];
    const float* conv_bias= (const float*)d_in[8];
    const float* bn_g     = (const float*)d_in[9];
    const float* bn_b     = (const float*)d_in[10];
    const float* mlp_w1   = (const float*)d_in[11];
    const float* mbn1_g   = (const float*)d_in[12];
    const float* mbn1_b   = (const float*)d_in[13];
    const float* mlp_w2   = (const float*)d_in[14];
    const float* mbn2_g   = (const float*)d_in[15];
    const float* mbn2_b   = (const float*)d_in[16];
    const float* mlp_w3   = (const float*)d_in[17];
    const float* mlp_b3   = (const float*)d_in[18];
    const int*   edge_idx = (const int*)d_in[19];
    const int*   batch    = (const int*)d_in[20];
    float* outp = (float*)d_out;

    const int N = in_sizes[20];
    const int E = in_sizes[19] / 2;
    const int G = out_size / 10;
    const int* esrc = edge_idx;
    const int* edst = edge_idx + E;

    int shift = 6;
    while ((((N - 1) >> shift) + 1) > NBMAX && shift < 7) ++shift;
    const int NB = ((N - 1) >> shift) + 1;

    char* p = (char*)d_ws;
    auto alloc = [&](size_t bytes) {
        char* r = p;
        p += (bytes + 255) & ~(size_t)255;
        return r;
    };
    float*          h      = (float*)alloc((size_t)N * 128 * 4);
    unsigned short* basesP = (unsigned short*)alloc((size_t)N * 64 * 2);
    unsigned short* combB16= (unsigned short*)alloc((size_t)N * 96 * 2);
    float*          outb   = (float*)alloc((size_t)N * 128 * 4);
    int*            csr    = (int*)  alloc((size_t)E * 4);
    int*            rowptr = (int*)  alloc((size_t)(N + 1) * 4);
    int*            bbase  = (int*)  alloc((size_t)(NB + 1) * 4);
    float*          tg     = (float*)alloc((size_t)G * 128 * 4);
    float*          t1     = (float*)alloc((size_t)G * 64 * 4);
    float*          t2     = (float*)alloc((size_t)G * 32 * 4);
    int*            gstart = (int*)  alloc((size_t)(G + 1) * 4);
    int*            bsum   = (int*)  alloc(512 * 4);
    char*           zbase  = p;
    int*            bcnt   = (int*)  alloc((size_t)NB * 4);
    int*            bcur0  = (int*)  alloc((size_t)NB * 4);
    float*          stats  = (float*)alloc(7 * 256 * 4);
    size_t zbytes = (size_t)(p - zbase);
    uint2* bucketed = (uint2*)combB16;   // alias: CSR build finishes before gemm writes combB16
    (void)ws_size; (void)n_in;

    hipMemsetAsync(zbase, 0, zbytes, stream);

    const float invN = 1.0f / (float)N;
    const float invG = 1.0f / (float)G;
    const int nbB = (NB + 255) / 256;

    // lin1 + BN1 stats
    k_lin1<<<1024, 256, 0, stream>>>(x, lin1_w, lin1_b, outb, stats, N);
    // bucketed CSR build
    k_p1_hist<<<256, 256, 0, stream>>>(edst, bcnt, E, NB, shift);
    k_scan1<<<nbB, 256, 0, stream>>>(bcnt, bbase, bsum, NB);
    k_scan2<<<1, 512, 0, stream>>>(bsum, nbB);
    k_scan3<<<nbB, 256, 0, stream>>>(bbase, bsum, NB, E);
    k_p2_scatter<<<(E + CHUNK - 1) / CHUNK, 256, 0, stream>>>(esrc, edst, bbase, bcur0,
                                                              bucketed, E, NB, shift);
    k_p3_csr<<<NB, 256, 0, stream>>>(bucketed, bbase, rowptr, csr, N, NB, shift);

    for (int l = 0; l < 4; ++l) {
        const float* bw = bases_w + (size_t)l * 128 * 64;
        const float* cw = comb_w + (size_t)l * 128 * 96;
        const float* cb = comb_b + (size_t)l * 96;
        const float* cvb = conv_bias + (size_t)l * 128;
        const float* pg = (l == 0) ? bn1_g : bn_g + (l - 1) * 128;
        const float* pb = (l == 0) ? bn1_b : bn_b + (l - 1) * 128;
        k_gemm_mfma<<<512, 256, 0, stream>>>(outb, h, stats + l * 256, pg, pb, invN,
                                             l > 0 ? 1 : 0, bw, cw, cb, basesP, combB16, N);
        k_agg<<<2048, 256, 0, stream>>>((const uint2*)basesP, combB16, csr, rowptr, cvb,
                                        outb, stats + (1 + l) * 256, N);
    }

    k_gbound<<<512, 256, 0, stream>>>(batch, gstart, N, G);
    k_gmean<<<G, 128, 0, stream>>>(outb, h, stats + 4 * 256, bn_g + 3 * 128,
                                   bn_b + 3 * 128, invN, gstart, tg, G);
    float* st5 = stats + 5 * 256;
    float* st6 = stats + 6 * 256;
    k_mlp1<<<G, 64, 0, stream>>>(tg, mlp_w1, t1, st5, G);
    k_mlp2<<<G, 64, 0, stream>>>(t1, st5, mbn1_g, mbn1_b, mlp_w2, t2, st6, invG, G);
    k_mlp3<<<G, 64, 0, stream>>>(t2, st6, mbn2_g, mbn2_b, mlp_w3, mlp_b3, outp, invG, G);
}

// Round 5
// 818.081 us; speedup vs baseline: 2.3681x; 1.0561x over previous
//
#include <hip/hip_runtime.h>

#define EPSV 1e-5f
#define NEGINF -3.402823466e38f
#define NBMAX 1600
#define CHUNK 8192
#define CAP3 6144

typedef short bf16x8 __attribute__((ext_vector_type(8)));
typedef float f32x4 __attribute__((ext_vector_type(4)));

__device__ __forceinline__ unsigned short f2bf(float f) {
    union { float f; unsigned i; } c; c.f = f;
    unsigned r = c.i + 0x7fff + ((c.i >> 16) & 1);
    return (unsigned short)(r >> 16);
}
__device__ __forceinline__ float blo(unsigned u) {
    union { unsigned i; float f; } c; c.i = u << 16; return c.f;
}
__device__ __forceinline__ float bhi(unsigned u) {
    union { unsigned i; float f; } c; c.i = u & 0xffff0000u; return c.f;
}

// ---------------------------------------------------------------- lin1 + stats
__global__ __launch_bounds__(256)
void k_lin1(const float* __restrict__ x, const float* __restrict__ w,
            const float* __restrict__ bvec, float* __restrict__ outb,
            float* __restrict__ stats, int N)
{
    __shared__ float wl[27 * 128];
    int tid = threadIdx.x;
    for (int i = tid; i < 27 * 128; i += 256) wl[i] = w[i];
    __syncthreads();

    int l  = tid & 63;
    int wv = tid >> 6;
    float bv0 = bvec[l], bv1 = bvec[64 + l];
    int waveSlots = gridDim.x * 4;
    int trips = (N + waveSlots - 1) / waveSlots;
    float s0 = 0.f, q0 = 0.f, s1 = 0.f, q1 = 0.f;
    for (int it = 0; it < trips; ++it) {
        int n = (it * gridDim.x + blockIdx.x) * 4 + wv;
        if (n < N) {
            const float* xr = x + (size_t)n * 27;
            float a0 = bv0, a1 = bv1;
            #pragma unroll
            for (int k = 0; k < 27; ++k) {
                float xv = xr[k];
                a0 = fmaf(xv, wl[k * 128 + l], a0);
                a1 = fmaf(xv, wl[k * 128 + 64 + l], a1);
            }
            outb[(size_t)n * 128 + l] = a0;
            outb[(size_t)n * 128 + 64 + l] = a1;
            s0 += a0; q0 += a0 * a0; s1 += a1; q1 += a1 * a1;
        }
    }
    __shared__ float sred[4][256];
    sred[0][tid] = s0; sred[1][tid] = q0;
    sred[2][tid] = s1; sred[3][tid] = q1;
    __syncthreads();
    if (tid < 64) {
        int t = tid;
        float v0 = sred[0][t] + sred[0][t + 64] + sred[0][t + 128] + sred[0][t + 192];
        float v1 = sred[1][t] + sred[1][t + 64] + sred[1][t + 128] + sred[1][t + 192];
        float v2 = sred[2][t] + sred[2][t + 64] + sred[2][t + 128] + sred[2][t + 192];
        float v3 = sred[3][t] + sred[3][t + 64] + sred[3][t + 128] + sred[3][t + 192];
        atomicAdd(stats + t, v0);
        atomicAdd(stats + 128 + t, v1);
        atomicAdd(stats + 64 + t, v2);
        atomicAdd(stats + 192 + t, v3);
    }
}

// ---------------------------------------------------------------- bucketed CSR build
__global__ __launch_bounds__(256)
void k_p1_hist(const int* __restrict__ dst, int* __restrict__ bcnt,
               int E, int NB, int shift)
{
    __shared__ int hist[NBMAX];
    for (int i = threadIdx.x; i < NB; i += 256) hist[i] = 0;
    __syncthreads();
    int stride = gridDim.x * 256;
    for (int e = blockIdx.x * 256 + threadIdx.x; e < E; e += stride)
        atomicAdd(&hist[dst[e] >> shift], 1);
    __syncthreads();
    for (int i = threadIdx.x; i < NB; i += 256)
        if (hist[i]) atomicAdd(bcnt + i, hist[i]);
}

__global__ void k_scan1(const int* __restrict__ cnt, int* __restrict__ rowptr,
                        int* __restrict__ bsum, int N)
{
    __shared__ int sb[256];
    int i = blockIdx.x * 256 + threadIdx.x;
    int v = (i < N) ? cnt[i] : 0;
    sb[threadIdx.x] = v;
    __syncthreads();
    for (int ofs = 1; ofs < 256; ofs <<= 1) {
        int u = (threadIdx.x >= ofs) ? sb[threadIdx.x - ofs] : 0;
        __syncthreads();
        sb[threadIdx.x] += u;
        __syncthreads();
    }
    if (i < N) rowptr[i] = sb[threadIdx.x] - v;
    if (threadIdx.x == 255) bsum[blockIdx.x] = sb[255];
}

__global__ void k_scan2(int* __restrict__ bs, int nb)
{
    __shared__ int sb[512];
    int t = threadIdx.x;
    int v = (t < nb) ? bs[t] : 0;
    sb[t] = v;
    __syncthreads();
    for (int ofs = 1; ofs < 512; ofs <<= 1) {
        int u = (t >= ofs) ? sb[t - ofs] : 0;
        __syncthreads();
        sb[t] += u;
        __syncthreads();
    }
    bs[t] = sb[t] - v;
}

__global__ void k_scan3(int* __restrict__ rowptr, const int* __restrict__ bsum,
                        int N, int E)
{
    int i = blockIdx.x * blockDim.x + threadIdx.x;
    if (i < N) rowptr[i] += bsum[i >> 8];
    if (i == 0) rowptr[N] = E;
}

__global__ __launch_bounds__(256)
void k_p2_scatter(const int* __restrict__ src, const int* __restrict__ dst,
                  const int* __restrict__ bbase, int* __restrict__ bcur0,
                  uint2* __restrict__ bucketed, int E, int NB, int shift)
{
    __shared__ uint2 ebuf[CHUNK];
    __shared__ int hist[NBMAX];
    __shared__ int cur[NBMAX];
    __shared__ int wtmp[256];
    int tid = threadIdx.x;
    int c0 = blockIdx.x * CHUNK;
    int cc = min(CHUNK, E - c0);
    if (cc <= 0) return;

    for (int i = tid; i < NB; i += 256) hist[i] = 0;
    __syncthreads();
    for (int i = tid; i < cc; i += 256)
        atomicAdd(&hist[dst[c0 + i] >> shift], 1);
    __syncthreads();
    int per = (NB + 255) / 256;
    int beg = tid * per, end = min(beg + per, NB);
    int s = 0;
    for (int i = beg; i < end; ++i) s += hist[i];
    wtmp[tid] = s;
    __syncthreads();
    for (int ofs = 1; ofs < 256; ofs <<= 1) {
        int u = (tid >= ofs) ? wtmp[tid - ofs] : 0;
        __syncthreads();
        wtmp[tid] += u;
        __syncthreads();
    }
    int run = wtmp[tid] - s;
    for (int i = beg; i < end; ++i) { cur[i] = run; run += hist[i]; }
    __syncthreads();
    for (int i = tid; i < cc; i += 256) {
        int sv = src[c0 + i], dv = dst[c0 + i];
        int b = dv >> shift;
        int pos = atomicAdd(&cur[b], 1);
        ebuf[pos] = make_uint2((unsigned)sv, (unsigned)dv);
    }
    __syncthreads();
    for (int b = tid; b < NB; b += 256) {
        int c = hist[b];
        if (c > 0) {
            int lb = cur[b] - c;
            int gb = bbase[b] + atomicAdd(&bcur0[b], c);
            hist[b] = gb - lb;
        }
    }
    __syncthreads();
    for (int i = tid; i < cc; i += 256) {
        uint2 u = ebuf[i];
        int b = (int)(u.y >> shift);
        bucketed[hist[b] + i] = u;
    }
}

__global__ __launch_bounds__(256)
void k_p3_csr(const uint2* __restrict__ bucketed, const int* __restrict__ bbase,
              int* __restrict__ rowptr, int* __restrict__ csr,
              int N, int NB, int shift)
{
    __shared__ int ncnt[128], nsc[128];
    __shared__ int lcsr[CAP3];
    int b = blockIdx.x;
    int tid = threadIdx.x;
    int e0 = bbase[b], e1 = bbase[b + 1];
    int cnt = e1 - e0;
    int node0 = b << shift;
    int nodes = min(1 << shift, N - node0);

    if (tid < 128) ncnt[tid] = 0;
    __syncthreads();
    for (int i = tid; i < cnt; i += 256)
        atomicAdd(&ncnt[(int)bucketed[e0 + i].y - node0], 1);
    __syncthreads();
    if (tid < 128) nsc[tid] = ncnt[tid];
    __syncthreads();
    for (int ofs = 1; ofs < 128; ofs <<= 1) {
        int u = 0;
        if (tid < 128 && tid >= ofs) u = nsc[tid - ofs];
        __syncthreads();
        if (tid < 128) nsc[tid] += u;
        __syncthreads();
    }
    if (tid < nodes) rowptr[node0 + tid] = e0 + nsc[tid] - ncnt[tid];
    if (tid == 0 && b == NB - 1) rowptr[N] = e1;
    if (tid < 128) ncnt[tid] = nsc[tid] - ncnt[tid];
    __syncthreads();
    if (cnt <= CAP3) {
        for (int i = tid; i < cnt; i += 256) {
            uint2 u = bucketed[e0 + i];
            int d = (int)u.y - node0;
            int pos = atomicAdd(&ncnt[d], 1);
            lcsr[pos] = (int)u.x;
        }
        __syncthreads();
        for (int i = tid; i < cnt; i += 256) csr[e0 + i] = lcsr[i];
    } else {
        for (int i = tid; i < cnt; i += 256) {
            uint2 u = bucketed[e0 + i];
            int d = (int)u.y - node0;
            int pos = atomicAdd(&ncnt[d], 1);
            csr[e0 + pos] = (int)u.x;
        }
    }
}

// ---------------------------------------------------------------- fused BN + MFMA GEMM
__global__ __launch_bounds__(256)
void k_gemm_mfma(const float* __restrict__ tin, float* __restrict__ h,
                 const float* __restrict__ stats, const float* __restrict__ gamma,
                 const float* __restrict__ beta, float invN, int residual,
                 const float* __restrict__ basesW, const float* __restrict__ combW,
                 const float* __restrict__ combB,
                 unsigned short* __restrict__ basesP,
                 unsigned short* __restrict__ combB16, int N)
{
    __shared__ unsigned short Wlds[2560 * 8];   // 40 KB
    __shared__ float scL[128], shL[128];
    int tid = threadIdx.x;
    if (tid < 128) {
        float mu  = stats[tid] * invN;
        float var = stats[128 + tid] * invN - mu * mu;
        float sc  = gamma[tid] * rsqrtf(var + EPSV);
        scL[tid] = sc;
        shL[tid] = beta[tid] - mu * sc;
    }
    for (int i = tid; i < 2560; i += 256) {
        int ct = i >> 8, rem = i & 255;
        int ln = rem & 63;
        int n16 = ln & 15, quad = ln >> 4;
        int k = ((rem >> 6) << 5) + quad * 8;
        unsigned short tmp[8];
        if (ct < 4) {
            int c = ct * 16 + n16;
            #pragma unroll
            for (int j = 0; j < 8; ++j) tmp[j] = f2bf(basesW[(k + j) * 64 + c]);
        } else {
            int c = (ct - 4) * 16 + n16;
            #pragma unroll
            for (int j = 0; j < 8; ++j) tmp[j] = f2bf(combW[(k + j) * 96 + c]);
        }
        uint4 pk;
        pk.x = (unsigned)tmp[0] | ((unsigned)tmp[1] << 16);
        pk.y = (unsigned)tmp[2] | ((unsigned)tmp[3] << 16);
        pk.z = (unsigned)tmp[4] | ((unsigned)tmp[5] << 16);
        pk.w = (unsigned)tmp[6] | ((unsigned)tmp[7] << 16);
        *(uint4*)&Wlds[(size_t)i * 8] = pk;
    }
    __syncthreads();

    int lane = tid & 63, wv = tid >> 6;
    int f = lane & 15, quad = lane >> 4;
    float cbv[6];
    #pragma unroll
    for (int s = 0; s < 6; ++s) cbv[s] = combB[s * 16 + f];

    int tiles = (N + 15) >> 4;
    int waveSlots = gridDim.x * 4;
    for (int tile = blockIdx.x * 4 + wv; tile < tiles; tile += waveSlots) {
        int tb = tile * 16;
        int mnode = min(tb + f, N - 1);
        size_t rbase = (size_t)mnode * 128;

        f32x4 acc[10];
        #pragma unroll
        for (int ct = 0; ct < 10; ++ct) acc[ct] = (f32x4){0.f, 0.f, 0.f, 0.f};

        #pragma unroll
        for (int ki = 0; ki < 4; ++ki) {
            int kc = quad * 8 + ki * 32;
            float4 t0 = *(const float4*)&tin[rbase + kc];
            float4 t1 = *(const float4*)&tin[rbase + kc + 4];
            float4 r0, r1;
            r0.x = fmaxf(t0.x * scL[kc]     + shL[kc],     0.f);
            r0.y = fmaxf(t0.y * scL[kc + 1] + shL[kc + 1], 0.f);
            r0.z = fmaxf(t0.z * scL[kc + 2] + shL[kc + 2], 0.f);
            r0.w = fmaxf(t0.w * scL[kc + 3] + shL[kc + 3], 0.f);
            r1.x = fmaxf(t1.x * scL[kc + 4] + shL[kc + 4], 0.f);
            r1.y = fmaxf(t1.y * scL[kc + 5] + shL[kc + 5], 0.f);
            r1.z = fmaxf(t1.z * scL[kc + 6] + shL[kc + 6], 0.f);
            r1.w = fmaxf(t1.w * scL[kc + 7] + shL[kc + 7], 0.f);
            if (residual) {
                float4 h0 = *(const float4*)&h[rbase + kc];
                float4 h1 = *(const float4*)&h[rbase + kc + 4];
                r0.x += h0.x; r0.y += h0.y; r0.z += h0.z; r0.w += h0.w;
                r1.x += h1.x; r1.y += h1.y; r1.z += h1.z; r1.w += h1.w;
            }
            *(float4*)&h[rbase + kc] = r0;
            *(float4*)&h[rbase + kc + 4] = r1;
            short ab[8];
            ab[0] = (short)f2bf(r0.x); ab[1] = (short)f2bf(r0.y);
            ab[2] = (short)f2bf(r0.z); ab[3] = (short)f2bf(r0.w);
            ab[4] = (short)f2bf(r1.x); ab[5] = (short)f2bf(r1.y);
            ab[6] = (short)f2bf(r1.z); ab[7] = (short)f2bf(r1.w);
            bf16x8 a = *(bf16x8*)ab;
            #pragma unroll
            for (int ct = 0; ct < 10; ++ct) {
                bf16x8 bfr = *(const bf16x8*)&Wlds[(size_t)((ct * 4 + ki) * 64 + lane) * 8];
                acc[ct] = __builtin_amdgcn_mfma_f32_16x16x32_bf16(a, bfr, acc[ct], 0, 0, 0);
            }
        }

        #pragma unroll
        for (int r = 0; r < 4; ++r) {
            int node = tb + quad * 4 + r;
            if (node < N) {
                #pragma unroll
                for (int ct = 0; ct < 4; ++ct)
                    basesP[(size_t)node * 64 + f * 4 + ct] = f2bf(acc[ct][r]);
                #pragma unroll
                for (int s = 0; s < 6; ++s)
                    combB16[(size_t)node * 96 + s * 16 + f] = f2bf(acc[4 + s][r] + cbv[s]);
            }
        }
    }
}

// ---------------------------------------------------------------- aggregation
// wave per node. lane l: f=l&15 owns 4 basis cols (uint2), sub=l>>4 owns edge
// slot e=4t+sub. Direct broadcast idx loads (no shfl), byte-offset addressing.
__global__ __launch_bounds__(256)
void k_agg(const unsigned short* __restrict__ basesP, const unsigned short* __restrict__ combB16,
           const int* __restrict__ csr, const int* __restrict__ rowptr,
           const float* __restrict__ cbias, float* __restrict__ outb,
           float* __restrict__ stats, int N)
{
    int l = threadIdx.x & 63;
    int w = threadIdx.x >> 6;
    int f = l & 15, sub = l >> 4;
    const char* bp = (const char*)basesP;
    unsigned fof = (unsigned)(f << 3);
    float cb0 = cbias[l], cb1 = cbias[64 + l];
    int waveSlots = gridDim.x * 4;
    int trips = (N + waveSlots - 1) / waveSlots;
    float s0 = 0.f, q0 = 0.f, s1 = 0.f, q1 = 0.f;

    for (int it = 0; it < trips; ++it) {
        int n = (it * gridDim.x + blockIdx.x) * 4 + w;
        if (n < N) {
            int row0 = rowptr[n], row1 = rowptr[n + 1];
            int cnt = row1 - row0;
            float S0 = 0.f, S1 = 0.f, S2 = 0.f, S3 = 0.f;
            float M0 = NEGINF, M1 = NEGINF, M2 = NEGINF, M3 = NEGINF;
            const int* cs = csr + row0 + sub;
            int tfull = cnt >> 2;
            #pragma unroll 4
            for (int t = 0; t < tfull; ++t) {
                int sn = cs[4 * t];
                uint2 u = *(const uint2*)(bp + (((unsigned)sn) << 7) + fof);
                float v0 = blo(u.x), v1 = bhi(u.x), v2 = blo(u.y), v3 = bhi(u.y);
                S0 += v0; S1 += v1; S2 += v2; S3 += v3;
                M0 = fmaxf(M0, v0); M1 = fmaxf(M1, v1);
                M2 = fmaxf(M2, v2); M3 = fmaxf(M3, v3);
            }
            int rem = cnt & 3;
            if (rem) {
                int e = (cnt & ~3) + sub;
                int sn = csr[row0 + min(e, cnt - 1)];
                uint2 u = *(const uint2*)(bp + (((unsigned)sn) << 7) + fof);
                if (sub < rem) {
                    float v0 = blo(u.x), v1 = bhi(u.x), v2 = blo(u.y), v3 = bhi(u.y);
                    S0 += v0; S1 += v1; S2 += v2; S3 += v3;
                    M0 = fmaxf(M0, v0); M1 = fmaxf(M1, v1);
                    M2 = fmaxf(M2, v2); M3 = fmaxf(M3, v3);
                }
            }
            // merge sub-partials
            S0 += __shfl_xor(S0, 16, 64); S1 += __shfl_xor(S1, 16, 64);
            S2 += __shfl_xor(S2, 16, 64); S3 += __shfl_xor(S3, 16, 64);
            S0 += __shfl_xor(S0, 32, 64); S1 += __shfl_xor(S1, 32, 64);
            S2 += __shfl_xor(S2, 32, 64); S3 += __shfl_xor(S3, 32, 64);
            M0 = fmaxf(M0, __shfl_xor(M0, 16, 64)); M1 = fmaxf(M1, __shfl_xor(M1, 16, 64));
            M2 = fmaxf(M2, __shfl_xor(M2, 16, 64)); M3 = fmaxf(M3, __shfl_xor(M3, 16, 64));
            M0 = fmaxf(M0, __shfl_xor(M0, 32, 64)); M1 = fmaxf(M1, __shfl_xor(M1, 32, 64));
            M2 = fmaxf(M2, __shfl_xor(M2, 32, 64)); M3 = fmaxf(M3, __shfl_xor(M3, 32, 64));
            // self loop
            uint2 su = *(const uint2*)(bp + (((unsigned)n) << 7) + fof);
            float w0 = blo(su.x), w1 = bhi(su.x), w2 = blo(su.y), w3 = bhi(su.y);
            S0 += w0; S1 += w1; S2 += w2; S3 += w3;
            M0 = fmaxf(M0, w0); M1 = fmaxf(M1, w1);
            M2 = fmaxf(M2, w2); M3 = fmaxf(M3, w3);
            float invd = 1.f / (float)(cnt + 1);
            float A0 = S0 * invd, A1 = S1 * invd, A2 = S2 * invd, A3 = S3 * invd;

            const unsigned short* cr = combB16 + (size_t)n * 96;
            const uint2* c0p = (const uint2*)(cr + sub * 12);
            const uint2* c1p = (const uint2*)(cr + 48 + sub * 12);
            uint2 qa0 = c0p[0], qa1 = c0p[1], qa2 = c0p[2];
            uint2 qb0 = c1p[0], qb1 = c1p[1], qb2 = c1p[2];

            float o0 = cb0, o1 = cb1;
            o0 = fmaf(blo(qa0.x), S0, o0); o0 = fmaf(bhi(qa0.x), S1, o0);
            o0 = fmaf(blo(qa0.y), S2, o0); o0 = fmaf(bhi(qa0.y), S3, o0);
            o0 = fmaf(blo(qa1.x), A0, o0); o0 = fmaf(bhi(qa1.x), A1, o0);
            o0 = fmaf(blo(qa1.y), A2, o0); o0 = fmaf(bhi(qa1.y), A3, o0);
            o0 = fmaf(blo(qa2.x), M0, o0); o0 = fmaf(bhi(qa2.x), M1, o0);
            o0 = fmaf(blo(qa2.y), M2, o0); o0 = fmaf(bhi(qa2.y), M3, o0);
            o1 = fmaf(blo(qb0.x), S0, o1); o1 = fmaf(bhi(qb0.x), S1, o1);
            o1 = fmaf(blo(qb0.y), S2, o1); o1 = fmaf(bhi(qb0.y), S3, o1);
            o1 = fmaf(blo(qb1.x), A0, o1); o1 = fmaf(bhi(qb1.x), A1, o1);
            o1 = fmaf(blo(qb1.y), A2, o1); o1 = fmaf(bhi(qb1.y), A3, o1);
            o1 = fmaf(blo(qb2.x), M0, o1); o1 = fmaf(bhi(qb2.x), M1, o1);
            o1 = fmaf(blo(qb2.y), M2, o1); o1 = fmaf(bhi(qb2.y), M3, o1);

            outb[(size_t)n * 128 + l] = o0;
            outb[(size_t)n * 128 + 64 + l] = o1;
            s0 += o0; q0 += o0 * o0; s1 += o1; q1 += o1 * o1;
        }
    }
    __shared__ float sred[4][256];
    sred[0][threadIdx.x] = s0; sred[1][threadIdx.x] = q0;
    sred[2][threadIdx.x] = s1; sred[3][threadIdx.x] = q1;
    __syncthreads();
    if (threadIdx.x < 64) {
        int t = threadIdx.x;
        float v0 = sred[0][t] + sred[0][t + 64] + sred[0][t + 128] + sred[0][t + 192];
        float v1 = sred[1][t] + sred[1][t + 64] + sred[1][t + 128] + sred[1][t + 192];
        float v2 = sred[2][t] + sred[2][t + 64] + sred[2][t + 128] + sred[2][t + 192];
        float v3 = sred[3][t] + sred[3][t + 64] + sred[3][t + 128] + sred[3][t + 192];
        atomicAdd(stats + t, v0);
        atomicAdd(stats + 128 + t, v1);
        atomicAdd(stats + 64 + t, v2);
        atomicAdd(stats + 192 + t, v3);
    }
}

// ---------------------------------------------------------------- pooling (fused final BN)
__global__ void k_gbound(const int* __restrict__ batch, int* __restrict__ gstart,
                         int N, int G)
{
    int stride = gridDim.x * blockDim.x;
    for (int n = blockIdx.x * blockDim.x + threadIdx.x; n < N; n += stride) {
        int b = batch[n];
        if (n == 0) {
            for (int g = 0; g <= b; ++g) gstart[g] = 0;
        } else {
            int pb = batch[n - 1];
            for (int g = pb + 1; g <= b; ++g) gstart[g] = n;
        }
        if (n == N - 1) {
            for (int g = b + 1; g <= G; ++g) gstart[g] = N;
        }
    }
}

__global__ __launch_bounds__(256)
void k_gmean(const float* __restrict__ t, const float* __restrict__ h,
             const float* __restrict__ stats, const float* __restrict__ gamma,
             const float* __restrict__ beta, float invN,
             const int* __restrict__ gstart, float* __restrict__ gout, int G)
{
    __shared__ float part[128];
    int g = blockIdx.x;
    if (g >= G) return;
    int c = threadIdx.x & 127;
    int half = threadIdx.x >> 7;
    float mu  = stats[c] * invN;
    float var = stats[128 + c] * invN - mu * mu;
    float sc  = gamma[c] * rsqrtf(var + EPSV);
    float sh  = beta[c] - mu * sc;
    int s = gstart[g], e = gstart[g + 1];
    float acc = 0.f;
    #pragma unroll 2
    for (int n = s + half; n < e; n += 2) {
        size_t o = (size_t)n * 128 + c;
        acc += h[o] + fmaxf(t[o] * sc + sh, 0.f);
    }
    if (half) part[c] = acc;
    __syncthreads();
    if (!half) {
        float tot = acc + part[c];
        float cntf = fmaxf((float)(e - s), 1.f);
        gout[g * 128 + c] = tot / cntf;
    }
}

// ---------------------------------------------------------------- MLP
__global__ void k_mlp1(const float* __restrict__ gin, const float* __restrict__ w1,
                       float* __restrict__ t1, float* __restrict__ stats, int G)
{
    int g = blockIdx.x;
    int c = threadIdx.x;
    const float* gr = gin + g * 128;
    float acc = 0.f;
    for (int k = 0; k < 128; ++k) acc = fmaf(gr[k], w1[k * 64 + c], acc);
    t1[g * 64 + c] = acc;
    atomicAdd(stats + c, acc);
    atomicAdd(stats + 64 + c, acc * acc);
}

__global__ void k_mlp2(const float* __restrict__ t1, const float* __restrict__ stats1,
                       const float* __restrict__ g1, const float* __restrict__ b1,
                       const float* __restrict__ w2, float* __restrict__ t2,
                       float* __restrict__ stats2, float invG, int G)
{
    __shared__ float row[64];
    int g = blockIdx.x;
    int c = threadIdx.x;
    float v = t1[g * 64 + c];
    float mu = stats1[c] * invG;
    float var = stats1[64 + c] * invG - mu * mu;
    row[c] = fmaxf(g1[c] * (v - mu) * rsqrtf(var + EPSV) + b1[c], 0.f);
    __syncthreads();
    if (c < 32) {
        float acc = 0.f;
        #pragma unroll
        for (int k = 0; k < 64; ++k) acc = fmaf(row[k], w2[k * 32 + c], acc);
        t2[g * 32 + c] = acc;
        atomicAdd(stats2 + c, acc);
        atomicAdd(stats2 + 32 + c, acc * acc);
    }
}

__global__ void k_mlp3(const float* __restrict__ t2, const float* __restrict__ stats2,
                       const float* __restrict__ g2, const float* __restrict__ b2,
                       const float* __restrict__ w3, const float* __restrict__ b3,
                       float* __restrict__ out, float invG, int G)
{
    __shared__ float row[32];
    int g = blockIdx.x;
    int c = threadIdx.x;
    if (c < 32) {
        float v = t2[g * 32 + c];
        float mu = stats2[c] * invG;
        float var = stats2[32 + c] * invG - mu * mu;
        row[c] = fmaxf(g2[c] * (v - mu) * rsqrtf(var + EPSV) + b2[c], 0.f);
    }
    __syncthreads();
    if (c < 10) {
        float acc = b3[c];
        #pragma unroll
        for (int k = 0; k < 32; ++k) acc = fmaf(row[k], w3[k * 10 + c], acc);
        out[g * 10 + c] = acc;
    }
}

// ---------------------------------------------------------------- launch
extern "C" void kernel_launch(void* const* d_in, const int* in_sizes, int n_in,
                              void* d_out, int out_size, void* d_ws, size_t ws_size,
                              hipStream_t stream)
{
    const float* x        = (const float*)d_in[0];
    const float* lin1_w   = (const float*)d_in[1];
    const float* lin1_b   = (const float*)d_in[2];
    const float* bn1_g    = (const float*)d_in[3];
    const float* bn1_b    = (const float*)d_in[4];
    const float* bases_w  = (const float*)d_in[5];
    const float* comb_w   = (const float*)d_in[6];
    const float* comb_b   = (const float*)d_in[7];
    const float* conv_bias= (const float*)d_in[8];
    const float* bn_g     = (const float*)d_in[9];
    const float* bn_b     = (const float*)d_in[10];
    const float* mlp_w1   = (const float*)d_in[11];
    const float* mbn1_g   = (const float*)d_in[12];
    const float* mbn1_b   = (const float*)d_in[13];
    const float* mlp_w2   = (const float*)d_in[14];
    const float* mbn2_g   = (const float*)d_in[15];
    const float* mbn2_b   = (const float*)d_in[16];
    const float* mlp_w3   = (const float*)d_in[17];
    const float* mlp_b3   = (const float*)d_in[18];
    const int*   edge_idx = (const int*)d_in[19];
    const int*   batch    = (const int*)d_in[20];
    float* outp = (float*)d_out;

    const int N = in_sizes[20];
    const int E = in_sizes[19] / 2;
    const int G = out_size / 10;
    const int* esrc = edge_idx;
    const int* edst = edge_idx + E;

    int shift = 6;
    while ((((N - 1) >> shift) + 1) > NBMAX && shift < 7) ++shift;
    const int NB = ((N - 1) >> shift) + 1;

    char* p = (char*)d_ws;
    auto alloc = [&](size_t bytes) {
        char* r = p;
        p += (bytes + 255) & ~(size_t)255;
        return r;
    };
    float*          h      = (float*)alloc((size_t)N * 128 * 4);
    unsigned short* basesP = (unsigned short*)alloc((size_t)N * 64 * 2);
    unsigned short* combB16= (unsigned short*)alloc((size_t)N * 96 * 2);
    float*          outb   = (float*)alloc((size_t)N * 128 * 4);
    int*            csr    = (int*)  alloc((size_t)E * 4);
    int*            rowptr = (int*)  alloc((size_t)(N + 1) * 4);
    int*            bbase  = (int*)  alloc((size_t)(NB + 1) * 4);
    float*          tg     = (float*)alloc((size_t)G * 128 * 4);
    float*          t1     = (float*)alloc((size_t)G * 64 * 4);
    float*          t2     = (float*)alloc((size_t)G * 32 * 4);
    int*            gstart = (int*)  alloc((size_t)(G + 1) * 4);
    int*            bsum   = (int*)  alloc(512 * 4);
    char*           zbase  = p;
    int*            bcnt   = (int*)  alloc((size_t)NB * 4);
    int*            bcur0  = (int*)  alloc((size_t)NB * 4);
    float*          stats  = (float*)alloc(7 * 256 * 4);
    size_t zbytes = (size_t)(p - zbase);
    uint2* bucketed = (uint2*)combB16;   // alias: CSR build done before gemm writes
    (void)ws_size; (void)n_in;

    hipMemsetAsync(zbase, 0, zbytes, stream);

    const float invN = 1.0f / (float)N;
    const float invG = 1.0f / (float)G;
    const int nbB = (NB + 255) / 256;

    k_lin1<<<1024, 256, 0, stream>>>(x, lin1_w, lin1_b, outb, stats, N);
    k_p1_hist<<<256, 256, 0, stream>>>(edst, bcnt, E, NB, shift);
    k_scan1<<<nbB, 256, 0, stream>>>(bcnt, bbase, bsum, NB);
    k_scan2<<<1, 512, 0, stream>>>(bsum, nbB);
    k_scan3<<<nbB, 256, 0, stream>>>(bbase, bsum, NB, E);
    k_p2_scatter<<<(E + CHUNK - 1) / CHUNK, 256, 0, stream>>>(esrc, edst, bbase, bcur0,
                                                              bucketed, E, NB, shift);
    k_p3_csr<<<NB, 256, 0, stream>>>(bucketed, bbase, rowptr, csr, N, NB, shift);

    for (int l = 0; l < 4; ++l) {
        const float* bw = bases_w + (size_t)l * 128 * 64;
        const float* cw = comb_w + (size_t)l * 128 * 96;
        const float* cb = comb_b + (size_t)l * 96;
        const float* cvb = conv_bias + (size_t)l * 128;
        const float* pg = (l == 0) ? bn1_g : bn_g + (l - 1) * 128;
        const float* pb = (l == 0) ? bn1_b : bn_b + (l - 1) * 128;
        k_gemm_mfma<<<512, 256, 0, stream>>>(outb, h, stats + l * 256, pg, pb, invN,
                                             l > 0 ? 1 : 0, bw, cw, cb, basesP, combB16, N);
        k_agg<<<2048, 256, 0, stream>>>(basesP, combB16, csr, rowptr, cvb,
                                        outb, stats + (1 + l) * 256, N);
    }

    k_gbound<<<512, 256, 0, stream>>>(batch, gstart, N, G);
    k_gmean<<<G, 256, 0, stream>>>(outb, h, stats + 4 * 256, bn_g + 3 * 128,
                                   bn_b + 3 * 128, invN, gstart, tg, G);
    float* st5 = stats + 5 * 256;
    float* st6 = stats + 6 * 256;
    k_mlp1<<<G, 64, 0, stream>>>(tg, mlp_w1, t1, st5, G);
    k_mlp2<<<G, 64, 0, stream>>>(t1, st5, mbn1_g, mbn1_b, mlp_w2, t2, st6, invG, G);
    k_mlp3<<<G, 64, 0, stream>>>(t2, st6, mbn2_g, mbn2_b, mlp_w3, mlp_b3, outp, invG, G);
}